// Round 2
// baseline (2145.440 us; speedup 1.0000x reference)
//
#include <hip/hip_runtime.h>

#define L_SZ   4096
#define B_SZ   4
#define NCOLS  16384      // B_SZ * L_SZ
#define DIM    768
#define DINNER 1536
#define E2     3072       // 2*DINNER
#define DTRANK 48
#define DSTATE 16
#define NCHUNK 64
#define CLEN   64         // L_SZ / NCHUNK

// perm within each (d,b) 4096-row: l = c*64 + w*4 + q  ->  off = w*256 + c*4 + q

typedef unsigned short ushortT;
typedef __attribute__((ext_vector_type(8))) short short8;
typedef __attribute__((ext_vector_type(4))) float floatx4;

__device__ __forceinline__ unsigned short f2bf(float f) {
  union { float f; unsigned u; } v; v.f = f;
  unsigned r = v.u + 0x7FFF + ((v.u >> 16) & 1);
  return (unsigned short)(r >> 16);
}
__device__ __forceinline__ float bf2f(unsigned short h) {
  union { unsigned u; float f; } v; v.u = ((unsigned)h) << 16;
  return v.f;
}

// ---------------- fp32 -> bf16 conversion ----------------
__global__ __launch_bounds__(256) void cvt_bf16_kernel(const float* __restrict__ in,
                                                       ushortT* __restrict__ out, int n4) {
  int i = blockIdx.x * 256 + threadIdx.x;
  if (i >= n4) return;
  float4 v = ((const float4*)in)[i];
  ushort4 o;
  o.x = f2bf(v.x); o.y = f2bf(v.y); o.z = f2bf(v.z); o.w = f2bf(v.w);
  ((ushort4*)out)[i] = o;
}

// ---------------- zero fill (float4 granules) ----------------
__global__ __launch_bounds__(256) void zero_kernel(float4* __restrict__ p) {
  p[blockIdx.x * 256 + threadIdx.x] = make_float4(0.f, 0.f, 0.f, 0.f);
}

// ---------------- bf16 NT GEMM: C[m,n] = sum_k A[m,k]*B[n,k] ----------------
__global__ __launch_bounds__(256) void gemm_nt(const ushortT* __restrict__ A,
                                               const ushortT* __restrict__ Bm,
                                               float* __restrict__ Cf, ushortT* __restrict__ Cb,
                                               int M, int N, int K, int out_bf16, int G)
{
  __shared__ ushortT As[128 * 64];
  __shared__ ushortT Bs[128 * 64];
  int tid = threadIdx.x;
  int wave = tid >> 6, lane = tid & 63;
  int gid = blockIdx.y * gridDim.x + blockIdx.x;
  int per_sg = G * gridDim.y;
  int sg = gid / per_sg, r = gid % per_sg;
  int bm = r / G;
  int bn = sg * G + (r % G);
  const ushortT* Abase = A + (size_t)bm * 128 * K;
  const ushortT* Bbase = Bm + (size_t)bn * 128 * K;
  int lm = lane & 15, lq = lane >> 4;
  int wm = (wave >> 1) * 64, wn = (wave & 1) * 64;
  int rloc = lane >> 3;
  int c_st = (lane & 7) * 8;
  floatx4 acc[4][4] = {};

  for (int k0 = 0; k0 < K; k0 += 64) {
    __syncthreads();
    #pragma unroll
    for (int j = 0; j < 4; j++) {
      int t = wave * 4 + j;
      const ushortT* ga = Abase + (size_t)(t * 8 + rloc) * K + k0 + c_st;
      const ushortT* gb = Bbase + (size_t)(t * 8 + rloc) * K + k0 + c_st;
      __builtin_amdgcn_global_load_lds((const __attribute__((address_space(1))) void*)ga,
                                       (__attribute__((address_space(3))) void*)(As + t * 512),
                                       16, 0, 0);
      __builtin_amdgcn_global_load_lds((const __attribute__((address_space(1))) void*)gb,
                                       (__attribute__((address_space(3))) void*)(Bs + t * 512),
                                       16, 0, 0);
    }
    __syncthreads();
    #pragma unroll
    for (int ks = 0; ks < 2; ks++) {
      short8 af[4], bfv[4];
      #pragma unroll
      for (int i = 0; i < 4; i++)
        af[i] = *(const short8*)(As + (wm + i * 16 + lm) * 64 + ks * 32 + lq * 8);
      #pragma unroll
      for (int j2 = 0; j2 < 4; j2++)
        bfv[j2] = *(const short8*)(Bs + (wn + j2 * 16 + lm) * 64 + ks * 32 + lq * 8);
      #pragma unroll
      for (int i = 0; i < 4; i++)
        #pragma unroll
        for (int j2 = 0; j2 < 4; j2++)
          acc[i][j2] = __builtin_amdgcn_mfma_f32_16x16x32_bf16(af[i], bfv[j2], acc[i][j2], 0, 0, 0);
    }
  }
  #pragma unroll
  for (int i = 0; i < 4; i++) {
    #pragma unroll
    for (int j2 = 0; j2 < 4; j2++) {
      int mg = bm * 128 + wm + i * 16 + lq * 4;
      int ng = bn * 128 + wn + j2 * 16 + lm;
      #pragma unroll
      for (int q = 0; q < 4; q++) {
        size_t off = (size_t)(mg + q) * N + ng;
        if (out_bf16) Cb[off] = f2bf(acc[i][j2][q]);
        else          Cf[off] = acc[i][j2][q];
      }
    }
  }
}

// ---------------- causal depthwise conv(k=4) + silu, bf16 in/out ----------------
__global__ __launch_bounds__(256) void conv_silu_kernel(const ushortT* __restrict__ xz,
                                                        const float* __restrict__ w,
                                                        const float* __restrict__ bias,
                                                        ushortT* __restrict__ xc, int reverse)
{
  int idx = blockIdx.x * 256 + threadIdx.x;
  int p4 = idx & 1023;
  int rb = idx >> 10;
  int b = rb & 3, d = rb >> 2;
  int wq = p4 >> 6, c = p4 & 63;
  int l0 = c * 64 + wq * 4;                    // plain (or reversed-seq) position
  const ushortT* xin = xz + (size_t)d * NCOLS + b * L_SZ;
  float w0 = w[d * 4], w1 = w[d * 4 + 1], w2 = w[d * 4 + 2], w3 = w[d * 4 + 3];
  float bv = bias[d];
  float xv[8];
  float r0, r1, r2, r3;
  if (!reverse) {
    if (l0 >= 4) {
      ushort4 a = *(const ushort4*)(xin + l0 - 4);
      ushort4 cc = *(const ushort4*)(xin + l0);
      xv[0]=bf2f(a.x); xv[1]=bf2f(a.y); xv[2]=bf2f(a.z); xv[3]=bf2f(a.w);
      xv[4]=bf2f(cc.x); xv[5]=bf2f(cc.y); xv[6]=bf2f(cc.z); xv[7]=bf2f(cc.w);
    } else {
      #pragma unroll
      for (int i = 0; i < 8; i++) { int p = l0 - 4 + i; xv[i] = (p >= 0) ? bf2f(xin[p]) : 0.f; }
    }
    r0 = bv + w0*xv[1] + w1*xv[2] + w2*xv[3] + w3*xv[4];
    r1 = bv + w0*xv[2] + w1*xv[3] + w2*xv[4] + w3*xv[5];
    r2 = bv + w0*xv[3] + w1*xv[4] + w2*xv[5] + w3*xv[6];
    r3 = bv + w0*xv[4] + w1*xv[5] + w2*xv[6] + w3*xv[7];
  } else {
    int base = 4092 - l0;
    if (l0 >= 4) {
      ushort4 a = *(const ushort4*)(xin + base);
      ushort4 cc = *(const ushort4*)(xin + base + 4);
      xv[0]=bf2f(a.x); xv[1]=bf2f(a.y); xv[2]=bf2f(a.z); xv[3]=bf2f(a.w);
      xv[4]=bf2f(cc.x); xv[5]=bf2f(cc.y); xv[6]=bf2f(cc.z); xv[7]=bf2f(cc.w);
    } else {
      #pragma unroll
      for (int i = 0; i < 8; i++) { int p = base + i; xv[i] = (p <= 4095) ? bf2f(xin[p]) : 0.f; }
    }
    r0 = bv + w0*xv[6] + w1*xv[5] + w2*xv[4] + w3*xv[3];
    r1 = bv + w0*xv[5] + w1*xv[4] + w2*xv[3] + w3*xv[2];
    r2 = bv + w0*xv[4] + w1*xv[3] + w2*xv[2] + w3*xv[1];
    r3 = bv + w0*xv[3] + w1*xv[2] + w2*xv[1] + w3*xv[0];
  }
  ushort4 o;
  o.x = f2bf(r0 / (1.f + __expf(-r0)));
  o.y = f2bf(r1 / (1.f + __expf(-r1)));
  o.z = f2bf(r2 / (1.f + __expf(-r2)));
  o.w = f2bf(r3 / (1.f + __expf(-r3)));
  *(ushort4*)(xc + (size_t)d * NCOLS + b * L_SZ + p4 * 4) = o;
}

// ---------------- x_proj GEMM (fp32 vector), K-split x3 + atomic accumulate ----------------
// grid (NCOLS/64, 3). Outputs must be pre-zeroed.
__global__ __launch_bounds__(256) void xdbl_kernel(const ushortT* __restrict__ xc,
                                                   const float* __restrict__ W, // (80,1536)
                                                   float* __restrict__ dtr,
                                                   float* __restrict__ Bt,
                                                   float* __restrict__ Ct)
{
  __shared__ float xcs[32 * 68];
  __shared__ float Ws[80 * 32];
  int tid = threadIdx.x;
  int n0 = blockIdx.x * 64;
  int kbase = blockIdx.y * 512;
  int tm = tid >> 4, tn = tid & 15;
  float acc[5][4] = {};
  for (int k0 = kbase; k0 < kbase + 512; k0 += 32) {
    __syncthreads();
    {
      int kk = tid >> 3, c8 = (tid & 7) * 8;
      const ushortT* src = xc + (size_t)(k0 + kk) * NCOLS + n0 + c8;
      ushort4 a = *(const ushort4*)src;
      ushort4 b = *(const ushort4*)(src + 4);
      float* dst = xcs + kk * 68 + c8;
      dst[0]=bf2f(a.x); dst[1]=bf2f(a.y); dst[2]=bf2f(a.z); dst[3]=bf2f(a.w);
      dst[4]=bf2f(b.x); dst[5]=bf2f(b.y); dst[6]=bf2f(b.z); dst[7]=bf2f(b.w);
    }
    for (int i = tid; i < 80 * 32; i += 256) {
      int m = i >> 5, kk = i & 31;
      Ws[i] = W[(size_t)m * DINNER + k0 + kk];
    }
    __syncthreads();
    #pragma unroll 8
    for (int kk = 0; kk < 32; kk++) {
      const float* xr = xcs + kk * 68 + tn * 4;
      float x0 = xr[0], x1 = xr[1], x2 = xr[2], x3 = xr[3];
      #pragma unroll
      for (int im = 0; im < 5; im++) {
        float wv = Ws[(tm * 5 + im) * 32 + kk];
        acc[im][0] += wv * x0; acc[im][1] += wv * x1;
        acc[im][2] += wv * x2; acc[im][3] += wv * x3;
      }
    }
  }
  #pragma unroll
  for (int im = 0; im < 5; im++) {
    int m = tm * 5 + im;
    #pragma unroll
    for (int j = 0; j < 4; j++) {
      int n = n0 + tn * 4 + j;
      float v = acc[im][j];
      if (m < 48)      atomicAdd(&dtr[(size_t)m * NCOLS + n], v);
      else if (m < 64) atomicAdd(&Bt[(size_t)n * 16 + (m - 48)], v);
      else             atomicAdd(&Ct[(size_t)n * 16 + (m - 64)], v);
    }
  }
}

// ---------------- dt = softplus(W @ dtr + bias), bf16 out (permuted cols) ----------------
__global__ __launch_bounds__(256) void dt_kernel(const float* __restrict__ dtr,
                                                 const float* __restrict__ W, // (1536,48)
                                                 const float* __restrict__ bias,
                                                 ushortT* __restrict__ dtb)
{
  __shared__ float sD[48 * 68];
  __shared__ float sW[48 * 68];
  int tid = threadIdx.x;
  int n0 = blockIdx.x * 64, d0 = blockIdx.y * 64;
  for (int i = tid; i < 48 * 64; i += 256) {
    int r = i >> 6, c = i & 63;
    sD[r * 68 + c] = dtr[(size_t)r * NCOLS + n0 + c];
  }
  for (int i = tid; i < 64 * 48; i += 256) {
    int dd = i / 48, k = i - dd * 48;
    sW[k * 68 + dd] = W[(size_t)d0 * 48 + i];
  }
  __syncthreads();
  int tn = tid & 15, tm = tid >> 4;
  float acc[4][4];
  #pragma unroll
  for (int i = 0; i < 4; i++) {
    float bv = bias[d0 + tm * 4 + i];
    #pragma unroll
    for (int j = 0; j < 4; j++) acc[i][j] = bv;
  }
  #pragma unroll 6
  for (int k = 0; k < 48; k++) {
    float4 wv = *(const float4*)(sW + k * 68 + tm * 4);
    float4 xv = *(const float4*)(sD + k * 68 + tn * 4);
    float wa[4] = { wv.x, wv.y, wv.z, wv.w };
    float xa[4] = { xv.x, xv.y, xv.z, xv.w };
    #pragma unroll
    for (int i = 0; i < 4; i++)
      #pragma unroll
      for (int j = 0; j < 4; j++)
        acc[i][j] += wa[i] * xa[j];
  }
  #pragma unroll
  for (int i = 0; i < 4; i++) {
    int d = d0 + tm * 4 + i;
    ushort4 o;
    float a0 = acc[i][0], a1 = acc[i][1], a2 = acc[i][2], a3 = acc[i][3];
    o.x = f2bf((a0 > 20.f) ? a0 : log1pf(__expf(a0)));
    o.y = f2bf((a1 > 20.f) ? a1 : log1pf(__expf(a1)));
    o.z = f2bf((a2 > 20.f) ? a2 : log1pf(__expf(a2)));
    o.w = f2bf((a3 > 20.f) ? a3 : log1pf(__expf(a3)));
    *(ushort4*)(dtb + (size_t)d * NCOLS + n0 + tn * 4) = o;
  }
}

// ---------------- chunked selective scan v5: one thread owns all 16 states ----------------
// Block 256 = 4 d-rows x 64 chunks (16 states/thread, no cross-lane shuffles).
// Pass 1: zero-state y1 = C.h0 + D.u, stored bf16 IN-PLACE over u (owner-exclusive);
//         chunk summaries h0_end (Hs) and S = sum(dt) (Ss).
// Combine: h_start per chunk.
// Pass 2 (chain-free): y = y1 + sum_n C[l,n] * exp2(Av2[n]*T_l) * h_start[n].
// Grid (DINNER/4, B_SZ) = (384,4).
__global__ __launch_bounds__(256) void scan_kernel5(ushortT* __restrict__ u,   // XC, y1 in-place
                                                    const ushortT* __restrict__ dt,
                                                    const float* __restrict__ Bt,
                                                    const float* __restrict__ Ct,
                                                    const float* __restrict__ A_log,
                                                    const float* __restrict__ Dp,
                                                    ushortT* __restrict__ y, int reverse)
{
  __shared__ float Hs[64 * 65];
  __shared__ float Ss[4 * 64];
  int tid = threadIdx.x;
  int c  = tid & 63;                 // chunk
  int dl = tid >> 6;                 // d-row within block (0..3)
  int b = blockIdx.y;
  int d = blockIdx.x * 4 + dl;

  float Av2[16];
  #pragma unroll
  for (int n = 0; n < 16; n++)
    Av2[n] = -__expf(A_log[d * 16 + n]) * 1.442695040888963f;  // A*log2(e)
  float Dv = Dp[d];

  ushortT* ur = u + (size_t)d * NCOLS + b * L_SZ + c * 4;
  const ushortT* tr = dt + (size_t)d * NCOLS + b * L_SZ + c * 4;
  const float*   Bp = Bt + (size_t)b * L_SZ * 16;
  const float*   Cp = Ct + (size_t)b * L_SZ * 16;

  float h[16];
  #pragma unroll
  for (int n = 0; n < 16; n++) h[n] = 0.f;
  float S = 0.f;

  // ---- pass 1: y1 + chunk summaries ----
  for (int w = 0; w < 16; w++) {
    ushort4 u4 = *(const ushort4*)(ur + w * 256);
    ushort4 t4 = *(const ushort4*)(tr + w * 256);
    float uv[4] = { bf2f(u4.x), bf2f(u4.y), bf2f(u4.z), bf2f(u4.w) };
    float tv[4] = { bf2f(t4.x), bf2f(t4.y), bf2f(t4.z), bf2f(t4.w) };
    const float4* bp4 = (const float4*)(Bp + (size_t)(w * 256 + c * 4) * 16);
    const float4* cp4 = (const float4*)(Cp + (size_t)(w * 256 + c * 4) * 16);
    float yo[4];
    #pragma unroll
    for (int q = 0; q < 4; q++) {
      float tq = tv[q];
      float dtu = tq * uv[q];
      float4 b0 = bp4[q * 4 + 0], b1 = bp4[q * 4 + 1], b2 = bp4[q * 4 + 2], b3 = bp4[q * 4 + 3];
      float4 c0 = cp4[q * 4 + 0], c1 = cp4[q * 4 + 1], c2 = cp4[q * 4 + 2], c3 = cp4[q * 4 + 3];
      float Bf[16] = { b0.x,b0.y,b0.z,b0.w, b1.x,b1.y,b1.z,b1.w,
                       b2.x,b2.y,b2.z,b2.w, b3.x,b3.y,b3.z,b3.w };
      float Cv[16] = { c0.x,c0.y,c0.z,c0.w, c1.x,c1.y,c1.z,c1.w,
                       c2.x,c2.y,c2.z,c2.w, c3.x,c3.y,c3.z,c3.w };
      float a0 = 0.f, a1 = 0.f, a2 = 0.f, a3 = 0.f;
      #pragma unroll
      for (int n = 0; n < 16; n += 4) {
        float e0 = exp2f(tq * Av2[n + 0]);
        float e1 = exp2f(tq * Av2[n + 1]);
        float e2 = exp2f(tq * Av2[n + 2]);
        float e3 = exp2f(tq * Av2[n + 3]);
        h[n + 0] = h[n + 0] * e0 + Bf[n + 0] * dtu;
        h[n + 1] = h[n + 1] * e1 + Bf[n + 1] * dtu;
        h[n + 2] = h[n + 2] * e2 + Bf[n + 2] * dtu;
        h[n + 3] = h[n + 3] * e3 + Bf[n + 3] * dtu;
        a0 += h[n + 0] * Cv[n + 0];
        a1 += h[n + 1] * Cv[n + 1];
        a2 += h[n + 2] * Cv[n + 2];
        a3 += h[n + 3] * Cv[n + 3];
      }
      yo[q] = (a0 + a1) + (a2 + a3) + Dv * uv[q];
      S += tq;
    }
    ushort4 o;
    o.x = f2bf(yo[0]); o.y = f2bf(yo[1]); o.z = f2bf(yo[2]); o.w = f2bf(yo[3]);
    *(ushort4*)(ur + w * 256) = o;               // y1 in-place over u
  }
  #pragma unroll
  for (int n = 0; n < 16; n++)
    Hs[(dl * 16 + n) * 65 + c] = h[n];
  Ss[dl * 64 + c] = S;
  __syncthreads();

  // ---- combine: 64 threads = (d-row, state); serial over 64 chunks ----
  if (tid < 64) {
    int dl2 = tid >> 4, n2 = tid & 15;
    float Ac = -__expf(A_log[(blockIdx.x * 4 + dl2) * 16 + n2]) * 1.442695040888963f;
    float hsv = 0.f;
    for (int cc = 0; cc < NCHUNK; cc++) {
      int idx = tid * 65 + cc;
      float tmp = Hs[idx];
      Hs[idx] = hsv;                   // h at chunk start
      hsv = exp2f(Ac * Ss[dl2 * 64 + cc]) * hsv + tmp;
    }
  }
  __syncthreads();
  float hsr[16];
  #pragma unroll
  for (int n = 0; n < 16; n++) hsr[n] = Hs[(dl * 16 + n) * 65 + c];

  // ---- pass 2 (chain-free): y = y1 + C . (exp2(Av2*T) ⊙ h_start) ----
  ushortT* yrow = y + (size_t)d * NCOLS + b * L_SZ;
  float T = 0.f;
  for (int w = 0; w < 16; w++) {
    ushort4 t4  = *(const ushort4*)(tr + w * 256);
    ushort4 y14 = *(const ushort4*)(ur + w * 256);
    float tv[4]  = { bf2f(t4.x), bf2f(t4.y), bf2f(t4.z), bf2f(t4.w) };
    float y1v[4] = { bf2f(y14.x), bf2f(y14.y), bf2f(y14.z), bf2f(y14.w) };
    const float4* cp4 = (const float4*)(Cp + (size_t)(w * 256 + c * 4) * 16);
    float yo[4];
    #pragma unroll
    for (int q = 0; q < 4; q++) {
      T += tv[q];
      float4 c0 = cp4[q * 4 + 0], c1 = cp4[q * 4 + 1], c2 = cp4[q * 4 + 2], c3 = cp4[q * 4 + 3];
      float Cv[16] = { c0.x,c0.y,c0.z,c0.w, c1.x,c1.y,c1.z,c1.w,
                       c2.x,c2.y,c2.z,c2.w, c3.x,c3.y,c3.z,c3.w };
      float a0 = 0.f, a1 = 0.f, a2 = 0.f, a3 = 0.f;
      #pragma unroll
      for (int n = 0; n < 16; n += 4) {
        a0 += (exp2f(Av2[n + 0] * T) * hsr[n + 0]) * Cv[n + 0];
        a1 += (exp2f(Av2[n + 1] * T) * hsr[n + 1]) * Cv[n + 1];
        a2 += (exp2f(Av2[n + 2] * T) * hsr[n + 2]) * Cv[n + 2];
        a3 += (exp2f(Av2[n + 3] * T) * hsr[n + 3]) * Cv[n + 3];
      }
      yo[q] = y1v[q] + (a0 + a1) + (a2 + a3);
    }
    if (!reverse) {
      ushort4 o;
      o.x = f2bf(yo[0]); o.y = f2bf(yo[1]); o.z = f2bf(yo[2]); o.w = f2bf(yo[3]);
      *(ushort4*)(yrow + w * 256 + c * 4) = o;
    } else {
      // plain l = 4095 - lrev maps to permuted (15-w)*256 + (63-c)*4 + (3-q)
      ushort4* dst = (ushort4*)(yrow + (15 - w) * 256 + (63 - c) * 4);
      ushort4 old = *dst;
      ushort4 o;
      o.x = f2bf(bf2f(old.x) + yo[3]);
      o.y = f2bf(bf2f(old.y) + yo[2]);
      o.z = f2bf(bf2f(old.z) + yo[1]);
      o.w = f2bf(bf2f(old.w) + yo[0]);
      *dst = o;
    }
  }
}

// ---------------- inner = bf16( y * silu(z) ), transposed to (n, d) ----------------
__global__ __launch_bounds__(256) void inner_kernel(const ushortT* __restrict__ y,
                                                    const ushortT* __restrict__ xz,
                                                    ushortT* __restrict__ innerb)
{
  __shared__ float tile[64 * 65];
  int n0 = blockIdx.x * 64, d0 = blockIdx.y * 64;
  int tid = threadIdx.x;
  int c = tid & 63, rq = tid >> 6;
  int bseg = n0 & ~4095;                        // b * L_SZ
  int cch = (n0 & 4095) >> 6;                   // chunk (fixed for this tile)
  int poff = bseg + cch * 4 + (c >> 2) * 256 + (c & 3);  // permuted column of plain n0+c
  #pragma unroll
  for (int r = 0; r < 16; r++) {
    int dd = rq + r * 4;
    float yv = bf2f(y[(size_t)(d0 + dd) * NCOLS + poff]);
    float zv = bf2f(xz[(size_t)(DINNER + d0 + dd) * NCOLS + n0 + c]);
    float sv = zv / (1.f + __expf(-zv));
    tile[dd * 65 + c] = yv * sv;
  }
  __syncthreads();
  #pragma unroll
  for (int r = 0; r < 16; r++) {
    int nn = rq + r * 4;
    innerb[(size_t)(n0 + nn) * DINNER + d0 + c] = f2bf(tile[c * 65 + nn]);
  }
}

extern "C" void kernel_launch(void* const* d_in, const int* in_sizes, int n_in,
                              void* d_out, int out_size, void* d_ws, size_t ws_size,
                              hipStream_t stream)
{
  const float* x          = (const float*)d_in[0];
  const float* in_proj_w  = (const float*)d_in[1];
  const float* out_proj_w = (const float*)d_in[2];
  const float* conv_w     = (const float*)d_in[3];
  const float* conv_b     = (const float*)d_in[4];
  const float* xproj_w    = (const float*)d_in[5];
  const float* dt_w       = (const float*)d_in[6];
  const float* dt_b       = (const float*)d_in[7];
  const float* A_log      = (const float*)d_in[8];
  const float* Dp         = (const float*)d_in[9];
  const float* conv_w_b   = (const float*)d_in[10];
  const float* conv_b_b   = (const float*)d_in[11];
  const float* xproj_w_b  = (const float*)d_in[12];
  const float* dt_w_b     = (const float*)d_in[13];
  const float* dt_b_b     = (const float*)d_in[14];
  const float* A_log_b    = (const float*)d_in[15];
  const float* D_b        = (const float*)d_in[16];

  // --- workspace layout (peak 199.25 MiB), DTB in d_out ---
  char* ws = (char*)d_ws;
  ushortT* XZ   = (ushortT*)(ws + 0);
  ushortT* XC   = (ushortT*)(ws + 100663296);
  ushortT* YB   = (ushortT*)(ws + 150994944);
  float*   DTR  = (float*)  (ws + 201326592);
  float*   BT   = (float*)  (ws + 204472320);
  float*   CT   = (float*)  (ws + 205520896);
  ushortT* WOB  = (ushortT*)(ws + 206569472);
  ushortT* XB   = (ushortT*)(ws + 100663296);  // overlay on XC region (P0/P1 only)
  ushortT* WIB  = (ushortT*)(ws + 150994944);  // overlay on YB region (P0/P1 only)
  ushortT* DTB  = (ushortT*)d_out;             // 48 MiB exactly
  ushortT* INNER = XZ;                         // overlay on XZ x-half
  float* OUT = (float*)d_out;

  // bf16 conversions
  cvt_bf16_kernel<<<12288, 256, 0, stream>>>(x, XB, 3145728);
  cvt_bf16_kernel<<<2304, 256, 0, stream>>>(in_proj_w, WIB, 589824);
  cvt_bf16_kernel<<<1152, 256, 0, stream>>>(out_proj_w, WOB, 294912);

  // xz = in_proj_w @ x^T : (3072 x 16384), bf16 out; G=16 swizzle for L2 reuse
  gemm_nt<<<dim3(128, 24), 256, 0, stream>>>(WIB, XB, nullptr, XZ, E2, NCOLS, DIM, 1, 16);

  // forward direction
  conv_silu_kernel<<<24576, 256, 0, stream>>>(XZ, conv_w, conv_b, XC, 0);
  zero_kernel<<<1280, 256, 0, stream>>>((float4*)DTR);   // DTR+BT+CT = 5 MiB
  xdbl_kernel<<<dim3(256, 3), 256, 0, stream>>>(XC, xproj_w, DTR, BT, CT);
  dt_kernel<<<dim3(256, 24), 256, 0, stream>>>(DTR, dt_w, dt_b, DTB);
  scan_kernel5<<<dim3(384, 4), 256, 0, stream>>>(XC, DTB, BT, CT, A_log, Dp, YB, 0);

  // reverse direction (reversed coords; y added at original positions, permuted layout)
  conv_silu_kernel<<<24576, 256, 0, stream>>>(XZ, conv_w_b, conv_b_b, XC, 1);
  zero_kernel<<<1280, 256, 0, stream>>>((float4*)DTR);
  xdbl_kernel<<<dim3(256, 3), 256, 0, stream>>>(XC, xproj_w_b, DTR, BT, CT);
  dt_kernel<<<dim3(256, 24), 256, 0, stream>>>(DTR, dt_w_b, dt_b_b, DTB);
  scan_kernel5<<<dim3(384, 4), 256, 0, stream>>>(XC, DTB, BT, CT, A_log_b, D_b, YB, 1);

  // inner = bf16( y * silu(z) ) transposed to (n, d); un-permutes y
  inner_kernel<<<dim3(256, 24), 256, 0, stream>>>(YB, XZ, INNER);

  // out = inner @ out_proj_w^T : (16384 x 768), fp32 out
  gemm_nt<<<dim3(6, 128), 256, 0, stream>>>(INNER, WOB, OUT, nullptr, NCOLS, DIM, DINNER, 0, 6);
}

// Round 3
// 1756.466 us; speedup vs baseline: 1.2215x; 1.2215x over previous
//
#include <hip/hip_runtime.h>

#define L_SZ   4096
#define B_SZ   4
#define NCOLS  16384      // B_SZ * L_SZ
#define DIM    768
#define DINNER 1536
#define E2     3072       // 2*DINNER
#define DTRANK 48
#define DSTATE 16
#define NCHUNK 64
#define CLEN   64         // L_SZ / NCHUNK

// perm within each (d,b) 4096-row: l = c*64 + w*4 + q  ->  off = w*256 + c*4 + q

typedef unsigned short ushortT;
typedef __attribute__((ext_vector_type(8))) short short8;
typedef __attribute__((ext_vector_type(4))) float floatx4;

__device__ __forceinline__ unsigned short f2bf(float f) {
  union { float f; unsigned u; } v; v.f = f;
  unsigned r = v.u + 0x7FFF + ((v.u >> 16) & 1);
  return (unsigned short)(r >> 16);
}
__device__ __forceinline__ float bf2f(unsigned short h) {
  union { unsigned u; float f; } v; v.u = ((unsigned)h) << 16;
  return v.f;
}

// ---------------- fp32 -> bf16 conversion ----------------
__global__ __launch_bounds__(256) void cvt_bf16_kernel(const float* __restrict__ in,
                                                       ushortT* __restrict__ out, int n4) {
  int i = blockIdx.x * 256 + threadIdx.x;
  if (i >= n4) return;
  float4 v = ((const float4*)in)[i];
  ushort4 o;
  o.x = f2bf(v.x); o.y = f2bf(v.y); o.z = f2bf(v.z); o.w = f2bf(v.w);
  ((ushort4*)out)[i] = o;
}

// ---------------- zero fill (float4 granules) ----------------
__global__ __launch_bounds__(256) void zero_kernel(float4* __restrict__ p) {
  p[blockIdx.x * 256 + threadIdx.x] = make_float4(0.f, 0.f, 0.f, 0.f);
}

// ---------------- bf16 NT GEMM: C[m,n] = sum_k A[m,k]*B[n,k] ----------------
__global__ __launch_bounds__(256) void gemm_nt(const ushortT* __restrict__ A,
                                               const ushortT* __restrict__ Bm,
                                               float* __restrict__ Cf, ushortT* __restrict__ Cb,
                                               int M, int N, int K, int out_bf16, int G)
{
  __shared__ ushortT As[128 * 64];
  __shared__ ushortT Bs[128 * 64];
  int tid = threadIdx.x;
  int wave = tid >> 6, lane = tid & 63;
  int gid = blockIdx.y * gridDim.x + blockIdx.x;
  int per_sg = G * gridDim.y;
  int sg = gid / per_sg, r = gid % per_sg;
  int bm = r / G;
  int bn = sg * G + (r % G);
  const ushortT* Abase = A + (size_t)bm * 128 * K;
  const ushortT* Bbase = Bm + (size_t)bn * 128 * K;
  int lm = lane & 15, lq = lane >> 4;
  int wm = (wave >> 1) * 64, wn = (wave & 1) * 64;
  int rloc = lane >> 3;
  int c_st = (lane & 7) * 8;
  floatx4 acc[4][4] = {};

  for (int k0 = 0; k0 < K; k0 += 64) {
    __syncthreads();
    #pragma unroll
    for (int j = 0; j < 4; j++) {
      int t = wave * 4 + j;
      const ushortT* ga = Abase + (size_t)(t * 8 + rloc) * K + k0 + c_st;
      const ushortT* gb = Bbase + (size_t)(t * 8 + rloc) * K + k0 + c_st;
      __builtin_amdgcn_global_load_lds((const __attribute__((address_space(1))) void*)ga,
                                       (__attribute__((address_space(3))) void*)(As + t * 512),
                                       16, 0, 0);
      __builtin_amdgcn_global_load_lds((const __attribute__((address_space(1))) void*)gb,
                                       (__attribute__((address_space(3))) void*)(Bs + t * 512),
                                       16, 0, 0);
    }
    __syncthreads();
    #pragma unroll
    for (int ks = 0; ks < 2; ks++) {
      short8 af[4], bfv[4];
      #pragma unroll
      for (int i = 0; i < 4; i++)
        af[i] = *(const short8*)(As + (wm + i * 16 + lm) * 64 + ks * 32 + lq * 8);
      #pragma unroll
      for (int j2 = 0; j2 < 4; j2++)
        bfv[j2] = *(const short8*)(Bs + (wn + j2 * 16 + lm) * 64 + ks * 32 + lq * 8);
      #pragma unroll
      for (int i = 0; i < 4; i++)
        #pragma unroll
        for (int j2 = 0; j2 < 4; j2++)
          acc[i][j2] = __builtin_amdgcn_mfma_f32_16x16x32_bf16(af[i], bfv[j2], acc[i][j2], 0, 0, 0);
    }
  }
  #pragma unroll
  for (int i = 0; i < 4; i++) {
    #pragma unroll
    for (int j2 = 0; j2 < 4; j2++) {
      int mg = bm * 128 + wm + i * 16 + lq * 4;
      int ng = bn * 128 + wn + j2 * 16 + lm;
      #pragma unroll
      for (int q = 0; q < 4; q++) {
        size_t off = (size_t)(mg + q) * N + ng;
        if (out_bf16) Cb[off] = f2bf(acc[i][j2][q]);
        else          Cf[off] = acc[i][j2][q];
      }
    }
  }
}

// ---------------- causal depthwise conv(k=4) + silu, bf16 in/out ----------------
__global__ __launch_bounds__(256) void conv_silu_kernel(const ushortT* __restrict__ xz,
                                                        const float* __restrict__ w,
                                                        const float* __restrict__ bias,
                                                        ushortT* __restrict__ xc, int reverse)
{
  int idx = blockIdx.x * 256 + threadIdx.x;
  int p4 = idx & 1023;
  int rb = idx >> 10;
  int b = rb & 3, d = rb >> 2;
  int wq = p4 >> 6, c = p4 & 63;
  int l0 = c * 64 + wq * 4;                    // plain (or reversed-seq) position
  const ushortT* xin = xz + (size_t)d * NCOLS + b * L_SZ;
  float w0 = w[d * 4], w1 = w[d * 4 + 1], w2 = w[d * 4 + 2], w3 = w[d * 4 + 3];
  float bv = bias[d];
  float xv[8];
  float r0, r1, r2, r3;
  if (!reverse) {
    if (l0 >= 4) {
      ushort4 a = *(const ushort4*)(xin + l0 - 4);
      ushort4 cc = *(const ushort4*)(xin + l0);
      xv[0]=bf2f(a.x); xv[1]=bf2f(a.y); xv[2]=bf2f(a.z); xv[3]=bf2f(a.w);
      xv[4]=bf2f(cc.x); xv[5]=bf2f(cc.y); xv[6]=bf2f(cc.z); xv[7]=bf2f(cc.w);
    } else {
      #pragma unroll
      for (int i = 0; i < 8; i++) { int p = l0 - 4 + i; xv[i] = (p >= 0) ? bf2f(xin[p]) : 0.f; }
    }
    r0 = bv + w0*xv[1] + w1*xv[2] + w2*xv[3] + w3*xv[4];
    r1 = bv + w0*xv[2] + w1*xv[3] + w2*xv[4] + w3*xv[5];
    r2 = bv + w0*xv[3] + w1*xv[4] + w2*xv[5] + w3*xv[6];
    r3 = bv + w0*xv[4] + w1*xv[5] + w2*xv[6] + w3*xv[7];
  } else {
    int base = 4092 - l0;
    if (l0 >= 4) {
      ushort4 a = *(const ushort4*)(xin + base);
      ushort4 cc = *(const ushort4*)(xin + base + 4);
      xv[0]=bf2f(a.x); xv[1]=bf2f(a.y); xv[2]=bf2f(a.z); xv[3]=bf2f(a.w);
      xv[4]=bf2f(cc.x); xv[5]=bf2f(cc.y); xv[6]=bf2f(cc.z); xv[7]=bf2f(cc.w);
    } else {
      #pragma unroll
      for (int i = 0; i < 8; i++) { int p = base + i; xv[i] = (p <= 4095) ? bf2f(xin[p]) : 0.f; }
    }
    r0 = bv + w0*xv[6] + w1*xv[5] + w2*xv[4] + w3*xv[3];
    r1 = bv + w0*xv[5] + w1*xv[4] + w2*xv[3] + w3*xv[2];
    r2 = bv + w0*xv[4] + w1*xv[3] + w2*xv[2] + w3*xv[1];
    r3 = bv + w0*xv[3] + w1*xv[2] + w2*xv[1] + w3*xv[0];
  }
  ushort4 o;
  o.x = f2bf(r0 / (1.f + __expf(-r0)));
  o.y = f2bf(r1 / (1.f + __expf(-r1)));
  o.z = f2bf(r2 / (1.f + __expf(-r2)));
  o.w = f2bf(r3 / (1.f + __expf(-r3)));
  *(ushort4*)(xc + (size_t)d * NCOLS + b * L_SZ + p4 * 4) = o;
}

// ---------------- x_proj GEMM (fp32 vector), K-split x3 + atomic accumulate ----------------
// grid (NCOLS/64, 3). Outputs must be pre-zeroed.
__global__ __launch_bounds__(256) void xdbl_kernel(const ushortT* __restrict__ xc,
                                                   const float* __restrict__ W, // (80,1536)
                                                   float* __restrict__ dtr,
                                                   float* __restrict__ Bt,
                                                   float* __restrict__ Ct)
{
  __shared__ float xcs[32 * 68];
  __shared__ float Ws[80 * 32];
  int tid = threadIdx.x;
  int n0 = blockIdx.x * 64;
  int kbase = blockIdx.y * 512;
  int tm = tid >> 4, tn = tid & 15;
  float acc[5][4] = {};
  for (int k0 = kbase; k0 < kbase + 512; k0 += 32) {
    __syncthreads();
    {
      int kk = tid >> 3, c8 = (tid & 7) * 8;
      const ushortT* src = xc + (size_t)(k0 + kk) * NCOLS + n0 + c8;
      ushort4 a = *(const ushort4*)src;
      ushort4 b = *(const ushort4*)(src + 4);
      float* dst = xcs + kk * 68 + c8;
      dst[0]=bf2f(a.x); dst[1]=bf2f(a.y); dst[2]=bf2f(a.z); dst[3]=bf2f(a.w);
      dst[4]=bf2f(b.x); dst[5]=bf2f(b.y); dst[6]=bf2f(b.z); dst[7]=bf2f(b.w);
    }
    for (int i = tid; i < 80 * 32; i += 256) {
      int m = i >> 5, kk = i & 31;
      Ws[i] = W[(size_t)m * DINNER + k0 + kk];
    }
    __syncthreads();
    #pragma unroll 8
    for (int kk = 0; kk < 32; kk++) {
      const float* xr = xcs + kk * 68 + tn * 4;
      float x0 = xr[0], x1 = xr[1], x2 = xr[2], x3 = xr[3];
      #pragma unroll
      for (int im = 0; im < 5; im++) {
        float wv = Ws[(tm * 5 + im) * 32 + kk];
        acc[im][0] += wv * x0; acc[im][1] += wv * x1;
        acc[im][2] += wv * x2; acc[im][3] += wv * x3;
      }
    }
  }
  #pragma unroll
  for (int im = 0; im < 5; im++) {
    int m = tm * 5 + im;
    #pragma unroll
    for (int j = 0; j < 4; j++) {
      int n = n0 + tn * 4 + j;
      float v = acc[im][j];
      if (m < 48)      atomicAdd(&dtr[(size_t)m * NCOLS + n], v);
      else if (m < 64) atomicAdd(&Bt[(size_t)n * 16 + (m - 48)], v);
      else             atomicAdd(&Ct[(size_t)n * 16 + (m - 64)], v);
    }
  }
}

// ---------------- dt = softplus(W @ dtr + bias), bf16 out (permuted cols) ----------------
__global__ __launch_bounds__(256) void dt_kernel(const float* __restrict__ dtr,
                                                 const float* __restrict__ W, // (1536,48)
                                                 const float* __restrict__ bias,
                                                 ushortT* __restrict__ dtb)
{
  __shared__ float sD[48 * 68];
  __shared__ float sW[48 * 68];
  int tid = threadIdx.x;
  int n0 = blockIdx.x * 64, d0 = blockIdx.y * 64;
  for (int i = tid; i < 48 * 64; i += 256) {
    int r = i >> 6, c = i & 63;
    sD[r * 68 + c] = dtr[(size_t)r * NCOLS + n0 + c];
  }
  for (int i = tid; i < 64 * 48; i += 256) {
    int dd = i / 48, k = i - dd * 48;
    sW[k * 68 + dd] = W[(size_t)d0 * 48 + i];
  }
  __syncthreads();
  int tn = tid & 15, tm = tid >> 4;
  float acc[4][4];
  #pragma unroll
  for (int i = 0; i < 4; i++) {
    float bv = bias[d0 + tm * 4 + i];
    #pragma unroll
    for (int j = 0; j < 4; j++) acc[i][j] = bv;
  }
  #pragma unroll 6
  for (int k = 0; k < 48; k++) {
    float4 wv = *(const float4*)(sW + k * 68 + tm * 4);
    float4 xv = *(const float4*)(sD + k * 68 + tn * 4);
    float wa[4] = { wv.x, wv.y, wv.z, wv.w };
    float xa[4] = { xv.x, xv.y, xv.z, xv.w };
    #pragma unroll
    for (int i = 0; i < 4; i++)
      #pragma unroll
      for (int j = 0; j < 4; j++)
        acc[i][j] += wa[i] * xa[j];
  }
  #pragma unroll
  for (int i = 0; i < 4; i++) {
    int d = d0 + tm * 4 + i;
    ushort4 o;
    float a0 = acc[i][0], a1 = acc[i][1], a2 = acc[i][2], a3 = acc[i][3];
    o.x = f2bf((a0 > 20.f) ? a0 : log1pf(__expf(a0)));
    o.y = f2bf((a1 > 20.f) ? a1 : log1pf(__expf(a1)));
    o.z = f2bf((a2 > 20.f) ? a2 : log1pf(__expf(a2)));
    o.w = f2bf((a3 > 20.f) ? a3 : log1pf(__expf(a3)));
    *(ushort4*)(dtb + (size_t)d * NCOLS + n0 + tn * 4) = o;
  }
}

// ---------------- chunked selective scan v6: v4 hf-split + batched shuffles ----------------
// Block 256 = 2 d-rows x 64 chunks x 2 state-halves (8 states/thread, VGPR<=64).
// Cross-lane sums batched per w-iteration (4 independent shuffles, one wait) instead of
// per-q dependent shuffle+wait; accumulators split into 2 chains; B/C bases hoisted per w.
// Grid (DINNER/2, B_SZ) = (768,4).
__global__ __launch_bounds__(256) void scan_kernel6(ushortT* __restrict__ u,   // XC, y1 in-place
                                                    const ushortT* __restrict__ dt,
                                                    const float* __restrict__ Bt,
                                                    const float* __restrict__ Ct,
                                                    const float* __restrict__ A_log,
                                                    const float* __restrict__ Dp,
                                                    ushortT* __restrict__ y, int reverse)
{
  __shared__ float Hs[32 * 65];
  __shared__ float Ss[2 * 64];
  int tid = threadIdx.x;
  int hf = tid & 1;                  // state half
  int c  = (tid >> 1) & 63;          // chunk
  int dl = tid >> 7;                 // d-row within block (0,1)
  int b = blockIdx.y;
  int d = blockIdx.x * 2 + dl;
  int ns0 = hf * 8;

  float Av2[8];
  #pragma unroll
  for (int n = 0; n < 8; n++)
    Av2[n] = -__expf(A_log[d * 16 + ns0 + n]) * 1.442695040888963f;  // A*log2(e)
  float Dv = Dp[d];

  ushortT* ur = u + (size_t)d * NCOLS + b * L_SZ + c * 4;
  const ushortT* tr = dt + (size_t)d * NCOLS + b * L_SZ + c * 4;
  const float*   Bp = Bt + (size_t)b * L_SZ * 16 + ns0;
  const float*   Cp = Ct + (size_t)b * L_SZ * 16 + ns0;

  float h[8];
  float S = 0.f;
  #pragma unroll
  for (int n = 0; n < 8; n++) h[n] = 0.f;

  // ---- pass 1: y1 + chunk summaries ----
  for (int w = 0; w < 16; w++) {
    ushort4 u4 = *(const ushort4*)(ur + w * 256);
    ushort4 t4 = *(const ushort4*)(tr + w * 256);
    float uv[4] = { bf2f(u4.x), bf2f(u4.y), bf2f(u4.z), bf2f(u4.w) };
    float tv[4] = { bf2f(t4.x), bf2f(t4.y), bf2f(t4.z), bf2f(t4.w) };
    const float* Bw = Bp + (size_t)(w * 256 + c * 4) * 16;
    const float* Cw = Cp + (size_t)(w * 256 + c * 4) * 16;
    float yo[4];
    #pragma unroll
    for (int q = 0; q < 4; q++) {
      float tq = tv[q];
      float dtu = tq * uv[q];
      float4 b0 = *(const float4*)(Bw + q * 16);
      float4 b1 = *(const float4*)(Bw + q * 16 + 4);
      float4 c0 = *(const float4*)(Cw + q * 16);
      float4 c1 = *(const float4*)(Cw + q * 16 + 4);
      float Bf[8] = { b0.x,b0.y,b0.z,b0.w, b1.x,b1.y,b1.z,b1.w };
      float Cv[8] = { c0.x,c0.y,c0.z,c0.w, c1.x,c1.y,c1.z,c1.w };
      float a0 = 0.f, a1 = 0.f;
      #pragma unroll
      for (int n = 0; n < 4; n++) {
        float e = exp2f(tq * Av2[n]);
        h[n] = h[n] * e + Bf[n] * dtu;
        a0 += h[n] * Cv[n];
      }
      #pragma unroll
      for (int n = 4; n < 8; n++) {
        float e = exp2f(tq * Av2[n]);
        h[n] = h[n] * e + Bf[n] * dtu;
        a1 += h[n] * Cv[n];
      }
      yo[q] = a0 + a1;
      S += tq;
    }
    // batched cross-lane sum (4 independent shuffles, one wait)
    float os0 = __shfl_xor(yo[0], 1);
    float os1 = __shfl_xor(yo[1], 1);
    float os2 = __shfl_xor(yo[2], 1);
    float os3 = __shfl_xor(yo[3], 1);
    if (hf == 0) {
      ushort4 o;
      o.x = f2bf(yo[0] + os0 + Dv * uv[0]);
      o.y = f2bf(yo[1] + os1 + Dv * uv[1]);
      o.z = f2bf(yo[2] + os2 + Dv * uv[2]);
      o.w = f2bf(yo[3] + os3 + Dv * uv[3]);
      *(ushort4*)(ur + w * 256) = o;               // y1 in-place over u
    }
  }
  #pragma unroll
  for (int n = 0; n < 8; n++)
    Hs[(dl * 16 + ns0 + n) * 65 + c] = h[n];
  if (hf == 0) Ss[dl * 64 + c] = S;
  __syncthreads();

  // ---- combine: 32 threads = (d-row, state); serial over 64 chunks ----
  if (tid < 32) {
    int dl2 = tid >> 4, n2 = tid & 15;
    float Ac = -__expf(A_log[(blockIdx.x * 2 + dl2) * 16 + n2]) * 1.442695040888963f;
    float hsv = 0.f;
    int row = tid;
    for (int cc = 0; cc < NCHUNK; cc++) {
      int idx = row * 65 + cc;
      float tmp = Hs[idx];
      Hs[idx] = hsv;                   // h at chunk start
      hsv = exp2f(Ac * Ss[dl2 * 64 + cc]) * hsv + tmp;
    }
  }
  __syncthreads();
  float hsr[8];
  #pragma unroll
  for (int n = 0; n < 8; n++) hsr[n] = Hs[(dl * 16 + ns0 + n) * 65 + c];

  // ---- pass 2 (chain-free): y = y1 + C . (exp2(Av2*T) ⊙ h_start) ----
  ushortT* yrow = y + (size_t)d * NCOLS + b * L_SZ;
  float T = 0.f;
  for (int w = 0; w < 16; w++) {
    ushort4 t4  = *(const ushort4*)(tr + w * 256);
    ushort4 y14 = *(const ushort4*)(ur + w * 256);
    float tv[4]  = { bf2f(t4.x), bf2f(t4.y), bf2f(t4.z), bf2f(t4.w) };
    float y1v[4] = { bf2f(y14.x), bf2f(y14.y), bf2f(y14.z), bf2f(y14.w) };
    const float* Cw = Cp + (size_t)(w * 256 + c * 4) * 16;
    float co[4];
    #pragma unroll
    for (int q = 0; q < 4; q++) {
      T += tv[q];
      float4 c0 = *(const float4*)(Cw + q * 16);
      float4 c1 = *(const float4*)(Cw + q * 16 + 4);
      float Cv[8] = { c0.x,c0.y,c0.z,c0.w, c1.x,c1.y,c1.z,c1.w };
      float a0 = 0.f, a1 = 0.f;
      #pragma unroll
      for (int n = 0; n < 4; n++)
        a0 += (exp2f(Av2[n] * T) * hsr[n]) * Cv[n];
      #pragma unroll
      for (int n = 4; n < 8; n++)
        a1 += (exp2f(Av2[n] * T) * hsr[n]) * Cv[n];
      co[q] = a0 + a1;
    }
    // batched cross-lane sum
    float os0 = __shfl_xor(co[0], 1);
    float os1 = __shfl_xor(co[1], 1);
    float os2 = __shfl_xor(co[2], 1);
    float os3 = __shfl_xor(co[3], 1);
    if (hf == 0) {
      float yq0 = y1v[0] + co[0] + os0;
      float yq1 = y1v[1] + co[1] + os1;
      float yq2 = y1v[2] + co[2] + os2;
      float yq3 = y1v[3] + co[3] + os3;
      if (!reverse) {
        ushort4 o;
        o.x = f2bf(yq0); o.y = f2bf(yq1); o.z = f2bf(yq2); o.w = f2bf(yq3);
        *(ushort4*)(yrow + w * 256 + c * 4) = o;
      } else {
        // plain l = 4095 - lrev maps to permuted (15-w)*256 + (63-c)*4 + (3-q)
        ushort4* dst = (ushort4*)(yrow + (15 - w) * 256 + (63 - c) * 4);
        ushort4 old = *dst;
        ushort4 o;
        o.x = f2bf(bf2f(old.x) + yq3);
        o.y = f2bf(bf2f(old.y) + yq2);
        o.z = f2bf(bf2f(old.z) + yq1);
        o.w = f2bf(bf2f(old.w) + yq0);
        *dst = o;
      }
    }
  }
}

// ---------------- inner = bf16( y * silu(z) ), transposed to (n, d) ----------------
__global__ __launch_bounds__(256) void inner_kernel(const ushortT* __restrict__ y,
                                                    const ushortT* __restrict__ xz,
                                                    ushortT* __restrict__ innerb)
{
  __shared__ float tile[64 * 65];
  int n0 = blockIdx.x * 64, d0 = blockIdx.y * 64;
  int tid = threadIdx.x;
  int c = tid & 63, rq = tid >> 6;
  int bseg = n0 & ~4095;                        // b * L_SZ
  int cch = (n0 & 4095) >> 6;                   // chunk (fixed for this tile)
  int poff = bseg + cch * 4 + (c >> 2) * 256 + (c & 3);  // permuted column of plain n0+c
  #pragma unroll
  for (int r = 0; r < 16; r++) {
    int dd = rq + r * 4;
    float yv = bf2f(y[(size_t)(d0 + dd) * NCOLS + poff]);
    float zv = bf2f(xz[(size_t)(DINNER + d0 + dd) * NCOLS + n0 + c]);
    float sv = zv / (1.f + __expf(-zv));
    tile[dd * 65 + c] = yv * sv;
  }
  __syncthreads();
  #pragma unroll
  for (int r = 0; r < 16; r++) {
    int nn = rq + r * 4;
    innerb[(size_t)(n0 + nn) * DINNER + d0 + c] = f2bf(tile[c * 65 + nn]);
  }
}

extern "C" void kernel_launch(void* const* d_in, const int* in_sizes, int n_in,
                              void* d_out, int out_size, void* d_ws, size_t ws_size,
                              hipStream_t stream)
{
  const float* x          = (const float*)d_in[0];
  const float* in_proj_w  = (const float*)d_in[1];
  const float* out_proj_w = (const float*)d_in[2];
  const float* conv_w     = (const float*)d_in[3];
  const float* conv_b     = (const float*)d_in[4];
  const float* xproj_w    = (const float*)d_in[5];
  const float* dt_w       = (const float*)d_in[6];
  const float* dt_b       = (const float*)d_in[7];
  const float* A_log      = (const float*)d_in[8];
  const float* Dp         = (const float*)d_in[9];
  const float* conv_w_b   = (const float*)d_in[10];
  const float* conv_b_b   = (const float*)d_in[11];
  const float* xproj_w_b  = (const float*)d_in[12];
  const float* dt_w_b     = (const float*)d_in[13];
  const float* dt_b_b     = (const float*)d_in[14];
  const float* A_log_b    = (const float*)d_in[15];
  const float* D_b        = (const float*)d_in[16];

  // --- workspace layout (peak 199.25 MiB), DTB in d_out ---
  char* ws = (char*)d_ws;
  ushortT* XZ   = (ushortT*)(ws + 0);
  ushortT* XC   = (ushortT*)(ws + 100663296);
  ushortT* YB   = (ushortT*)(ws + 150994944);
  float*   DTR  = (float*)  (ws + 201326592);
  float*   BT   = (float*)  (ws + 204472320);
  float*   CT   = (float*)  (ws + 205520896);
  ushortT* WOB  = (ushortT*)(ws + 206569472);
  ushortT* XB   = (ushortT*)(ws + 100663296);  // overlay on XC region (P0/P1 only)
  ushortT* WIB  = (ushortT*)(ws + 150994944);  // overlay on YB region (P0/P1 only)
  ushortT* DTB  = (ushortT*)d_out;             // 48 MiB exactly
  ushortT* INNER = XZ;                         // overlay on XZ x-half
  float* OUT = (float*)d_out;

  // bf16 conversions
  cvt_bf16_kernel<<<12288, 256, 0, stream>>>(x, XB, 3145728);
  cvt_bf16_kernel<<<2304, 256, 0, stream>>>(in_proj_w, WIB, 589824);
  cvt_bf16_kernel<<<1152, 256, 0, stream>>>(out_proj_w, WOB, 294912);

  // xz = in_proj_w @ x^T : (3072 x 16384), bf16 out; G=16 swizzle for L2 reuse
  gemm_nt<<<dim3(128, 24), 256, 0, stream>>>(WIB, XB, nullptr, XZ, E2, NCOLS, DIM, 1, 16);

  // forward direction
  conv_silu_kernel<<<24576, 256, 0, stream>>>(XZ, conv_w, conv_b, XC, 0);
  zero_kernel<<<1280, 256, 0, stream>>>((float4*)DTR);   // DTR+BT+CT = 5 MiB
  xdbl_kernel<<<dim3(256, 3), 256, 0, stream>>>(XC, xproj_w, DTR, BT, CT);
  dt_kernel<<<dim3(256, 24), 256, 0, stream>>>(DTR, dt_w, dt_b, DTB);
  scan_kernel6<<<dim3(768, 4), 256, 0, stream>>>(XC, DTB, BT, CT, A_log, Dp, YB, 0);

  // reverse direction (reversed coords; y added at original positions, permuted layout)
  conv_silu_kernel<<<24576, 256, 0, stream>>>(XZ, conv_w_b, conv_b_b, XC, 1);
  zero_kernel<<<1280, 256, 0, stream>>>((float4*)DTR);
  xdbl_kernel<<<dim3(256, 3), 256, 0, stream>>>(XC, xproj_w_b, DTR, BT, CT);
  dt_kernel<<<dim3(256, 24), 256, 0, stream>>>(DTR, dt_w_b, dt_b_b, DTB);
  scan_kernel6<<<dim3(768, 4), 256, 0, stream>>>(XC, DTB, BT, CT, A_log_b, D_b, YB, 1);

  // inner = bf16( y * silu(z) ) transposed to (n, d); un-permutes y
  inner_kernel<<<dim3(256, 24), 256, 0, stream>>>(YB, XZ, INNER);

  // out = inner @ out_proj_w^T : (16384 x 768), fp32 out
  gemm_nt<<<dim3(6, 128), 256, 0, stream>>>(INNER, WOB, OUT, nullptr, NCOLS, DIM, DINNER, 0, 6);
}

// Round 5
// 1729.494 us; speedup vs baseline: 1.2405x; 1.0156x over previous
//
#include <hip/hip_runtime.h>

#define L_SZ   4096
#define B_SZ   4
#define NCOLS  16384      // B_SZ * L_SZ
#define DIM    768
#define DINNER 1536
#define E2     3072       // 2*DINNER
#define DTRANK 48
#define DSTATE 16
#define NCHUNK 64
#define CLEN   64         // L_SZ / NCHUNK

// perm within each (d,b) 4096-row: l = c*64 + w*4 + q  ->  off = w*256 + c*4 + q

typedef unsigned short ushortT;
typedef __attribute__((ext_vector_type(8))) short short8;
typedef __attribute__((ext_vector_type(4))) float floatx4;

__device__ __forceinline__ unsigned short f2bf(float f) {
  union { float f; unsigned u; } v; v.f = f;
  unsigned r = v.u + 0x7FFF + ((v.u >> 16) & 1);
  return (unsigned short)(r >> 16);
}
__device__ __forceinline__ float bf2f(unsigned short h) {
  union { unsigned u; float f; } v; v.u = ((unsigned)h) << 16;
  return v.f;
}

// native exp2: single v_exp_f32, no OCML denormal fixup (inputs here are
// moderate-negative products; flush-to-zero below ~-126 is fine).
__device__ __forceinline__ float ex2(float x) {
#if defined(__has_builtin)
#if __has_builtin(__builtin_amdgcn_exp2f)
  return __builtin_amdgcn_exp2f(x);
#else
  return exp2f(x);
#endif
#else
  return exp2f(x);
#endif
}

// ---------------- fp32 -> bf16 conversion ----------------
__global__ __launch_bounds__(256) void cvt_bf16_kernel(const float* __restrict__ in,
                                                       ushortT* __restrict__ out, int n4) {
  int i = blockIdx.x * 256 + threadIdx.x;
  if (i >= n4) return;
  float4 v = ((const float4*)in)[i];
  ushort4 o;
  o.x = f2bf(v.x); o.y = f2bf(v.y); o.z = f2bf(v.z); o.w = f2bf(v.w);
  ((ushort4*)out)[i] = o;
}

// ---------------- zero fill (float4 granules) ----------------
__global__ __launch_bounds__(256) void zero_kernel(float4* __restrict__ p) {
  p[blockIdx.x * 256 + threadIdx.x] = make_float4(0.f, 0.f, 0.f, 0.f);
}

// ---------------- bf16 NT GEMM: C[m,n] = sum_k A[m,k]*B[n,k] ----------------
__global__ __launch_bounds__(256) void gemm_nt(const ushortT* __restrict__ A,
                                               const ushortT* __restrict__ Bm,
                                               float* __restrict__ Cf, ushortT* __restrict__ Cb,
                                               int M, int N, int K, int out_bf16, int G)
{
  __shared__ ushortT As[128 * 64];
  __shared__ ushortT Bs[128 * 64];
  int tid = threadIdx.x;
  int wave = tid >> 6, lane = tid & 63;
  int gid = blockIdx.y * gridDim.x + blockIdx.x;
  int per_sg = G * gridDim.y;
  int sg = gid / per_sg, r = gid % per_sg;
  int bm = r / G;
  int bn = sg * G + (r % G);
  const ushortT* Abase = A + (size_t)bm * 128 * K;
  const ushortT* Bbase = Bm + (size_t)bn * 128 * K;
  int lm = lane & 15, lq = lane >> 4;
  int wm = (wave >> 1) * 64, wn = (wave & 1) * 64;
  int rloc = lane >> 3;
  int c_st = (lane & 7) * 8;
  floatx4 acc[4][4] = {};

  for (int k0 = 0; k0 < K; k0 += 64) {
    __syncthreads();
    #pragma unroll
    for (int j = 0; j < 4; j++) {
      int t = wave * 4 + j;
      const ushortT* ga = Abase + (size_t)(t * 8 + rloc) * K + k0 + c_st;
      const ushortT* gb = Bbase + (size_t)(t * 8 + rloc) * K + k0 + c_st;
      __builtin_amdgcn_global_load_lds((const __attribute__((address_space(1))) void*)ga,
                                       (__attribute__((address_space(3))) void*)(As + t * 512),
                                       16, 0, 0);
      __builtin_amdgcn_global_load_lds((const __attribute__((address_space(1))) void*)gb,
                                       (__attribute__((address_space(3))) void*)(Bs + t * 512),
                                       16, 0, 0);
    }
    __syncthreads();
    #pragma unroll
    for (int ks = 0; ks < 2; ks++) {
      short8 af[4], bfv[4];
      #pragma unroll
      for (int i = 0; i < 4; i++)
        af[i] = *(const short8*)(As + (wm + i * 16 + lm) * 64 + ks * 32 + lq * 8);
      #pragma unroll
      for (int j2 = 0; j2 < 4; j2++)
        bfv[j2] = *(const short8*)(Bs + (wn + j2 * 16 + lm) * 64 + ks * 32 + lq * 8);
      #pragma unroll
      for (int i = 0; i < 4; i++)
        #pragma unroll
        for (int j2 = 0; j2 < 4; j2++)
          acc[i][j2] = __builtin_amdgcn_mfma_f32_16x16x32_bf16(af[i], bfv[j2], acc[i][j2], 0, 0, 0);
    }
  }
  #pragma unroll
  for (int i = 0; i < 4; i++) {
    #pragma unroll
    for (int j2 = 0; j2 < 4; j2++) {
      int mg = bm * 128 + wm + i * 16 + lq * 4;
      int ng = bn * 128 + wn + j2 * 16 + lm;
      #pragma unroll
      for (int q = 0; q < 4; q++) {
        size_t off = (size_t)(mg + q) * N + ng;
        if (out_bf16) Cb[off] = f2bf(acc[i][j2][q]);
        else          Cf[off] = acc[i][j2][q];
      }
    }
  }
}

// ---------------- causal depthwise conv(k=4) + silu, bf16 in/out ----------------
__global__ __launch_bounds__(256) void conv_silu_kernel(const ushortT* __restrict__ xz,
                                                        const float* __restrict__ w,
                                                        const float* __restrict__ bias,
                                                        ushortT* __restrict__ xc, int reverse)
{
  int idx = blockIdx.x * 256 + threadIdx.x;
  int p4 = idx & 1023;
  int rb = idx >> 10;
  int b = rb & 3, d = rb >> 2;
  int wq = p4 >> 6, c = p4 & 63;
  int l0 = c * 64 + wq * 4;                    // plain (or reversed-seq) position
  const ushortT* xin = xz + (size_t)d * NCOLS + b * L_SZ;
  float w0 = w[d * 4], w1 = w[d * 4 + 1], w2 = w[d * 4 + 2], w3 = w[d * 4 + 3];
  float bv = bias[d];
  float xv[8];
  float r0, r1, r2, r3;
  if (!reverse) {
    if (l0 >= 4) {
      ushort4 a = *(const ushort4*)(xin + l0 - 4);
      ushort4 cc = *(const ushort4*)(xin + l0);
      xv[0]=bf2f(a.x); xv[1]=bf2f(a.y); xv[2]=bf2f(a.z); xv[3]=bf2f(a.w);
      xv[4]=bf2f(cc.x); xv[5]=bf2f(cc.y); xv[6]=bf2f(cc.z); xv[7]=bf2f(cc.w);
    } else {
      #pragma unroll
      for (int i = 0; i < 8; i++) { int p = l0 - 4 + i; xv[i] = (p >= 0) ? bf2f(xin[p]) : 0.f; }
    }
    r0 = bv + w0*xv[1] + w1*xv[2] + w2*xv[3] + w3*xv[4];
    r1 = bv + w0*xv[2] + w1*xv[3] + w2*xv[4] + w3*xv[5];
    r2 = bv + w0*xv[3] + w1*xv[4] + w2*xv[5] + w3*xv[6];
    r3 = bv + w0*xv[4] + w1*xv[5] + w2*xv[6] + w3*xv[7];
  } else {
    int base = 4092 - l0;
    if (l0 >= 4) {
      ushort4 a = *(const ushort4*)(xin + base);
      ushort4 cc = *(const ushort4*)(xin + base + 4);
      xv[0]=bf2f(a.x); xv[1]=bf2f(a.y); xv[2]=bf2f(a.z); xv[3]=bf2f(a.w);
      xv[4]=bf2f(cc.x); xv[5]=bf2f(cc.y); xv[6]=bf2f(cc.z); xv[7]=bf2f(cc.w);
    } else {
      #pragma unroll
      for (int i = 0; i < 8; i++) { int p = base + i; xv[i] = (p <= 4095) ? bf2f(xin[p]) : 0.f; }
    }
    r0 = bv + w0*xv[6] + w1*xv[5] + w2*xv[4] + w3*xv[3];
    r1 = bv + w0*xv[5] + w1*xv[4] + w2*xv[3] + w3*xv[2];
    r2 = bv + w0*xv[4] + w1*xv[3] + w2*xv[2] + w3*xv[1];
    r3 = bv + w0*xv[3] + w1*xv[2] + w2*xv[1] + w3*xv[0];
  }
  ushort4 o;
  o.x = f2bf(r0 / (1.f + __expf(-r0)));
  o.y = f2bf(r1 / (1.f + __expf(-r1)));
  o.z = f2bf(r2 / (1.f + __expf(-r2)));
  o.w = f2bf(r3 / (1.f + __expf(-r3)));
  *(ushort4*)(xc + (size_t)d * NCOLS + b * L_SZ + p4 * 4) = o;
}

// ---------------- x_proj GEMM (fp32 vector), K-split x3 + atomic accumulate ----------------
// grid (NCOLS/64, 3). Outputs must be pre-zeroed.
__global__ __launch_bounds__(256) void xdbl_kernel(const ushortT* __restrict__ xc,
                                                   const float* __restrict__ W, // (80,1536)
                                                   float* __restrict__ dtr,
                                                   float* __restrict__ Bt,
                                                   float* __restrict__ Ct)
{
  __shared__ float xcs[32 * 68];
  __shared__ float Ws[80 * 32];
  int tid = threadIdx.x;
  int n0 = blockIdx.x * 64;
  int kbase = blockIdx.y * 512;
  int tm = tid >> 4, tn = tid & 15;
  float acc[5][4] = {};
  for (int k0 = kbase; k0 < kbase + 512; k0 += 32) {
    __syncthreads();
    {
      int kk = tid >> 3, c8 = (tid & 7) * 8;
      const ushortT* src = xc + (size_t)(k0 + kk) * NCOLS + n0 + c8;
      ushort4 a = *(const ushort4*)src;
      ushort4 b = *(const ushort4*)(src + 4);
      float* dst = xcs + kk * 68 + c8;
      dst[0]=bf2f(a.x); dst[1]=bf2f(a.y); dst[2]=bf2f(a.z); dst[3]=bf2f(a.w);
      dst[4]=bf2f(b.x); dst[5]=bf2f(b.y); dst[6]=bf2f(b.z); dst[7]=bf2f(b.w);
    }
    for (int i = tid; i < 80 * 32; i += 256) {
      int m = i >> 5, kk = i & 31;
      Ws[i] = W[(size_t)m * DINNER + k0 + kk];
    }
    __syncthreads();
    #pragma unroll 8
    for (int kk = 0; kk < 32; kk++) {
      const float* xr = xcs + kk * 68 + tn * 4;
      float x0 = xr[0], x1 = xr[1], x2 = xr[2], x3 = xr[3];
      #pragma unroll
      for (int im = 0; im < 5; im++) {
        float wv = Ws[(tm * 5 + im) * 32 + kk];
        acc[im][0] += wv * x0; acc[im][1] += wv * x1;
        acc[im][2] += wv * x2; acc[im][3] += wv * x3;
      }
    }
  }
  #pragma unroll
  for (int im = 0; im < 5; im++) {
    int m = tm * 5 + im;
    #pragma unroll
    for (int j = 0; j < 4; j++) {
      int n = n0 + tn * 4 + j;
      float v = acc[im][j];
      if (m < 48)      atomicAdd(&dtr[(size_t)m * NCOLS + n], v);
      else if (m < 64) atomicAdd(&Bt[(size_t)n * 16 + (m - 48)], v);
      else             atomicAdd(&Ct[(size_t)n * 16 + (m - 64)], v);
    }
  }
}

// ---------------- dt = softplus(W @ dtr + bias), bf16 out (permuted cols) ----------------
__global__ __launch_bounds__(256) void dt_kernel(const float* __restrict__ dtr,
                                                 const float* __restrict__ W, // (1536,48)
                                                 const float* __restrict__ bias,
                                                 ushortT* __restrict__ dtb)
{
  __shared__ float sD[48 * 68];
  __shared__ float sW[48 * 68];
  int tid = threadIdx.x;
  int n0 = blockIdx.x * 64, d0 = blockIdx.y * 64;
  for (int i = tid; i < 48 * 64; i += 256) {
    int r = i >> 6, c = i & 63;
    sD[r * 68 + c] = dtr[(size_t)r * NCOLS + n0 + c];
  }
  for (int i = tid; i < 64 * 48; i += 256) {
    int dd = i / 48, k = i - dd * 48;
    sW[k * 68 + dd] = W[(size_t)d0 * 48 + i];
  }
  __syncthreads();
  int tn = tid & 15, tm = tid >> 4;
  float acc[4][4];
  #pragma unroll
  for (int i = 0; i < 4; i++) {
    float bv = bias[d0 + tm * 4 + i];
    #pragma unroll
    for (int j = 0; j < 4; j++) acc[i][j] = bv;
  }
  #pragma unroll 6
  for (int k = 0; k < 48; k++) {
    float4 wv = *(const float4*)(sW + k * 68 + tm * 4);
    float4 xv = *(const float4*)(sD + k * 68 + tn * 4);
    float wa[4] = { wv.x, wv.y, wv.z, wv.w };
    float xa[4] = { xv.x, xv.y, xv.z, xv.w };
    #pragma unroll
    for (int i = 0; i < 4; i++)
      #pragma unroll
      for (int j = 0; j < 4; j++)
        acc[i][j] += wa[i] * xa[j];
  }
  #pragma unroll
  for (int i = 0; i < 4; i++) {
    int d = d0 + tm * 4 + i;
    ushort4 o;
    float a0 = acc[i][0], a1 = acc[i][1], a2 = acc[i][2], a3 = acc[i][3];
    o.x = f2bf((a0 > 20.f) ? a0 : log1pf(__expf(a0)));
    o.y = f2bf((a1 > 20.f) ? a1 : log1pf(__expf(a1)));
    o.z = f2bf((a2 > 20.f) ? a2 : log1pf(__expf(a2)));
    o.w = f2bf((a3 > 20.f) ? a3 : log1pf(__expf(a3)));
    *(ushort4*)(dtb + (size_t)d * NCOLS + n0 + tn * 4) = o;
  }
}

// ---------------- chunked selective scan v7: v6 structure + native exp2 ----------------
// Block 256 = 2 d-rows x 64 chunks x 2 state-halves (8 states/thread).
// All exp2 via native v_exp_f32 (no OCML denormal fixup).
// Grid (DINNER/2, B_SZ) = (768,4).
__global__ __launch_bounds__(256) void scan_kernel7(ushortT* __restrict__ u,   // XC, y1 in-place
                                                    const ushortT* __restrict__ dt,
                                                    const float* __restrict__ Bt,
                                                    const float* __restrict__ Ct,
                                                    const float* __restrict__ A_log,
                                                    const float* __restrict__ Dp,
                                                    ushortT* __restrict__ y, int reverse)
{
  __shared__ float Hs[32 * 65];
  __shared__ float Ss[2 * 64];
  int tid = threadIdx.x;
  int hf = tid & 1;                  // state half
  int c  = (tid >> 1) & 63;          // chunk
  int dl = tid >> 7;                 // d-row within block (0,1)
  int b = blockIdx.y;
  int d = blockIdx.x * 2 + dl;
  int ns0 = hf * 8;

  float Av2[8];
  #pragma unroll
  for (int n = 0; n < 8; n++)
    Av2[n] = -__expf(A_log[d * 16 + ns0 + n]) * 1.442695040888963f;  // A*log2(e)
  float Dv = Dp[d];

  ushortT* ur = u + (size_t)d * NCOLS + b * L_SZ + c * 4;
  const ushortT* tr = dt + (size_t)d * NCOLS + b * L_SZ + c * 4;
  const float*   Bp = Bt + (size_t)b * L_SZ * 16 + ns0;
  const float*   Cp = Ct + (size_t)b * L_SZ * 16 + ns0;

  float h[8];
  float S = 0.f;
  #pragma unroll
  for (int n = 0; n < 8; n++) h[n] = 0.f;

  // ---- pass 1: y1 + chunk summaries ----
  for (int w = 0; w < 16; w++) {
    ushort4 u4 = *(const ushort4*)(ur + w * 256);
    ushort4 t4 = *(const ushort4*)(tr + w * 256);
    float uv[4] = { bf2f(u4.x), bf2f(u4.y), bf2f(u4.z), bf2f(u4.w) };
    float tv[4] = { bf2f(t4.x), bf2f(t4.y), bf2f(t4.z), bf2f(t4.w) };
    const float* Bw = Bp + (size_t)(w * 256 + c * 4) * 16;
    const float* Cw = Cp + (size_t)(w * 256 + c * 4) * 16;
    float yo[4];
    #pragma unroll
    for (int q = 0; q < 4; q++) {
      float tq = tv[q];
      float dtu = tq * uv[q];
      float4 b0 = *(const float4*)(Bw + q * 16);
      float4 b1 = *(const float4*)(Bw + q * 16 + 4);
      float4 c0 = *(const float4*)(Cw + q * 16);
      float4 c1 = *(const float4*)(Cw + q * 16 + 4);
      float Bf[8] = { b0.x,b0.y,b0.z,b0.w, b1.x,b1.y,b1.z,b1.w };
      float Cv[8] = { c0.x,c0.y,c0.z,c0.w, c1.x,c1.y,c1.z,c1.w };
      float a0 = 0.f, a1 = 0.f;
      #pragma unroll
      for (int n = 0; n < 4; n++) {
        float e = ex2(tq * Av2[n]);
        h[n] = h[n] * e + Bf[n] * dtu;
        a0 += h[n] * Cv[n];
      }
      #pragma unroll
      for (int n = 4; n < 8; n++) {
        float e = ex2(tq * Av2[n]);
        h[n] = h[n] * e + Bf[n] * dtu;
        a1 += h[n] * Cv[n];
      }
      yo[q] = a0 + a1;
      S += tq;
    }
    // batched cross-lane sum (4 independent shuffles, one wait)
    float os0 = __shfl_xor(yo[0], 1);
    float os1 = __shfl_xor(yo[1], 1);
    float os2 = __shfl_xor(yo[2], 1);
    float os3 = __shfl_xor(yo[3], 1);
    if (hf == 0) {
      ushort4 o;
      o.x = f2bf(yo[0] + os0 + Dv * uv[0]);
      o.y = f2bf(yo[1] + os1 + Dv * uv[1]);
      o.z = f2bf(yo[2] + os2 + Dv * uv[2]);
      o.w = f2bf(yo[3] + os3 + Dv * uv[3]);
      *(ushort4*)(ur + w * 256) = o;               // y1 in-place over u
    }
  }
  #pragma unroll
  for (int n = 0; n < 8; n++)
    Hs[(dl * 16 + ns0 + n) * 65 + c] = h[n];
  if (hf == 0) Ss[dl * 64 + c] = S;
  __syncthreads();

  // ---- combine: 32 threads = (d-row, state); serial over 64 chunks ----
  if (tid < 32) {
    int dl2 = tid >> 4, n2 = tid & 15;
    float Ac = -__expf(A_log[(blockIdx.x * 2 + dl2) * 16 + n2]) * 1.442695040888963f;
    float hsv = 0.f;
    int row = tid;
    for (int cc = 0; cc < NCHUNK; cc++) {
      int idx = row * 65 + cc;
      float tmp = Hs[idx];
      Hs[idx] = hsv;                   // h at chunk start
      hsv = ex2(Ac * Ss[dl2 * 64 + cc]) * hsv + tmp;
    }
  }
  __syncthreads();
  float hsr[8];
  #pragma unroll
  for (int n = 0; n < 8; n++) hsr[n] = Hs[(dl * 16 + ns0 + n) * 65 + c];

  // ---- pass 2 (chain-free): y = y1 + C . (exp2(Av2*T) ⊙ h_start) ----
  ushortT* yrow = y + (size_t)d * NCOLS + b * L_SZ;
  float T = 0.f;
  for (int w = 0; w < 16; w++) {
    ushort4 t4  = *(const ushort4*)(tr + w * 256);
    ushort4 y14 = *(const ushort4*)(ur + w * 256);
    float tv[4]  = { bf2f(t4.x), bf2f(t4.y), bf2f(t4.z), bf2f(t4.w) };
    float y1v[4] = { bf2f(y14.x), bf2f(y14.y), bf2f(y14.z), bf2f(y14.w) };
    const float* Cw = Cp + (size_t)(w * 256 + c * 4) * 16;
    float co[4];
    #pragma unroll
    for (int q = 0; q < 4; q++) {
      T += tv[q];
      float4 c0 = *(const float4*)(Cw + q * 16);
      float4 c1 = *(const float4*)(Cw + q * 16 + 4);
      float Cv[8] = { c0.x,c0.y,c0.z,c0.w, c1.x,c1.y,c1.z,c1.w };
      float a0 = 0.f, a1 = 0.f;
      #pragma unroll
      for (int n = 0; n < 4; n++)
        a0 += (ex2(Av2[n] * T) * hsr[n]) * Cv[n];
      #pragma unroll
      for (int n = 4; n < 8; n++)
        a1 += (ex2(Av2[n] * T) * hsr[n]) * Cv[n];
      co[q] = a0 + a1;
    }
    // batched cross-lane sum
    float os0 = __shfl_xor(co[0], 1);
    float os1 = __shfl_xor(co[1], 1);
    float os2 = __shfl_xor(co[2], 1);
    float os3 = __shfl_xor(co[3], 1);
    if (hf == 0) {
      float yq0 = y1v[0] + co[0] + os0;
      float yq1 = y1v[1] + co[1] + os1;
      float yq2 = y1v[2] + co[2] + os2;
      float yq3 = y1v[3] + co[3] + os3;
      if (!reverse) {
        ushort4 o;
        o.x = f2bf(yq0); o.y = f2bf(yq1); o.z = f2bf(yq2); o.w = f2bf(yq3);
        *(ushort4*)(yrow + w * 256 + c * 4) = o;
      } else {
        // plain l = 4095 - lrev maps to permuted (15-w)*256 + (63-c)*4 + (3-q)
        ushort4* dst = (ushort4*)(yrow + (15 - w) * 256 + (63 - c) * 4);
        ushort4 old = *dst;
        ushort4 o;
        o.x = f2bf(bf2f(old.x) + yq3);
        o.y = f2bf(bf2f(old.y) + yq2);
        o.z = f2bf(bf2f(old.z) + yq1);
        o.w = f2bf(bf2f(old.w) + yq0);
        *dst = o;
      }
    }
  }
}

// ---------------- inner = bf16( y * silu(z) ), transposed to (n, d) ----------------
__global__ __launch_bounds__(256) void inner_kernel(const ushortT* __restrict__ y,
                                                    const ushortT* __restrict__ xz,
                                                    ushortT* __restrict__ innerb)
{
  __shared__ float tile[64 * 65];
  int n0 = blockIdx.x * 64, d0 = blockIdx.y * 64;
  int tid = threadIdx.x;
  int c = tid & 63, rq = tid >> 6;
  int bseg = n0 & ~4095;                        // b * L_SZ
  int cch = (n0 & 4095) >> 6;                   // chunk (fixed for this tile)
  int poff = bseg + cch * 4 + (c >> 2) * 256 + (c & 3);  // permuted column of plain n0+c
  #pragma unroll
  for (int r = 0; r < 16; r++) {
    int dd = rq + r * 4;
    float yv = bf2f(y[(size_t)(d0 + dd) * NCOLS + poff]);
    float zv = bf2f(xz[(size_t)(DINNER + d0 + dd) * NCOLS + n0 + c]);
    float sv = zv / (1.f + __expf(-zv));
    tile[dd * 65 + c] = yv * sv;
  }
  __syncthreads();
  #pragma unroll
  for (int r = 0; r < 16; r++) {
    int nn = rq + r * 4;
    innerb[(size_t)(n0 + nn) * DINNER + d0 + c] = f2bf(tile[c * 65 + nn]);
  }
}

extern "C" void kernel_launch(void* const* d_in, const int* in_sizes, int n_in,
                              void* d_out, int out_size, void* d_ws, size_t ws_size,
                              hipStream_t stream)
{
  const float* x          = (const float*)d_in[0];
  const float* in_proj_w  = (const float*)d_in[1];
  const float* out_proj_w = (const float*)d_in[2];
  const float* conv_w     = (const float*)d_in[3];
  const float* conv_b     = (const float*)d_in[4];
  const float* xproj_w    = (const float*)d_in[5];
  const float* dt_w       = (const float*)d_in[6];
  const float* dt_b       = (const float*)d_in[7];
  const float* A_log      = (const float*)d_in[8];
  const float* Dp         = (const float*)d_in[9];
  const float* conv_w_b   = (const float*)d_in[10];
  const float* conv_b_b   = (const float*)d_in[11];
  const float* xproj_w_b  = (const float*)d_in[12];
  const float* dt_w_b     = (const float*)d_in[13];
  const float* dt_b_b     = (const float*)d_in[14];
  const float* A_log_b    = (const float*)d_in[15];
  const float* D_b        = (const float*)d_in[16];

  // --- workspace layout (peak 199.25 MiB), DTB in d_out ---
  char* ws = (char*)d_ws;
  ushortT* XZ   = (ushortT*)(ws + 0);
  ushortT* XC   = (ushortT*)(ws + 100663296);
  ushortT* YB   = (ushortT*)(ws + 150994944);
  float*   DTR  = (float*)  (ws + 201326592);
  float*   BT   = (float*)  (ws + 204472320);
  float*   CT   = (float*)  (ws + 205520896);
  ushortT* WOB  = (ushortT*)(ws + 206569472);
  ushortT* XB   = (ushortT*)(ws + 100663296);  // overlay on XC region (P0/P1 only)
  ushortT* WIB  = (ushortT*)(ws + 150994944);  // overlay on YB region (P0/P1 only)
  ushortT* DTB  = (ushortT*)d_out;             // 48 MiB exactly
  ushortT* INNER = XZ;                         // overlay on XZ x-half
  float* OUT = (float*)d_out;

  // bf16 conversions
  cvt_bf16_kernel<<<12288, 256, 0, stream>>>(x, XB, 3145728);
  cvt_bf16_kernel<<<2304, 256, 0, stream>>>(in_proj_w, WIB, 589824);
  cvt_bf16_kernel<<<1152, 256, 0, stream>>>(out_proj_w, WOB, 294912);

  // xz = in_proj_w @ x^T : (3072 x 16384), bf16 out; G=16 swizzle for L2 reuse
  gemm_nt<<<dim3(128, 24), 256, 0, stream>>>(WIB, XB, nullptr, XZ, E2, NCOLS, DIM, 1, 16);

  // forward direction
  conv_silu_kernel<<<24576, 256, 0, stream>>>(XZ, conv_w, conv_b, XC, 0);
  zero_kernel<<<1280, 256, 0, stream>>>((float4*)DTR);   // DTR+BT+CT = 5 MiB
  xdbl_kernel<<<dim3(256, 3), 256, 0, stream>>>(XC, xproj_w, DTR, BT, CT);
  dt_kernel<<<dim3(256, 24), 256, 0, stream>>>(DTR, dt_w, dt_b, DTB);
  scan_kernel7<<<dim3(768, 4), 256, 0, stream>>>(XC, DTB, BT, CT, A_log, Dp, YB, 0);

  // reverse direction (reversed coords; y added at original positions, permuted layout)
  conv_silu_kernel<<<24576, 256, 0, stream>>>(XZ, conv_w_b, conv_b_b, XC, 1);
  zero_kernel<<<1280, 256, 0, stream>>>((float4*)DTR);
  xdbl_kernel<<<dim3(256, 3), 256, 0, stream>>>(XC, xproj_w_b, DTR, BT, CT);
  dt_kernel<<<dim3(256, 24), 256, 0, stream>>>(DTR, dt_w_b, dt_b_b, DTB);
  scan_kernel7<<<dim3(768, 4), 256, 0, stream>>>(XC, DTB, BT, CT, A_log_b, D_b, YB, 1);

  // inner = bf16( y * silu(z) ) transposed to (n, d); un-permutes y
  inner_kernel<<<dim3(256, 24), 256, 0, stream>>>(YB, XZ, INNER);

  // out = inner @ out_proj_w^T : (16384 x 768), fp32 out
  gemm_nt<<<dim3(6, 128), 256, 0, stream>>>(INNER, WOB, OUT, nullptr, NCOLS, DIM, DINNER, 0, 6);
}

// Round 6
// 1591.034 us; speedup vs baseline: 1.3485x; 1.0870x over previous
//
#include <hip/hip_runtime.h>

#define L_SZ   4096
#define B_SZ   4
#define NCOLS  16384      // B_SZ * L_SZ
#define DIM    768
#define DINNER 1536
#define E2     3072       // 2*DINNER
#define DTRANK 48
#define DSTATE 16
#define NCHUNK 64
#define CLEN   64         // L_SZ / NCHUNK

// perm within each (d,b) 4096-row: l = c*64 + w*4 + q  ->  off = w*256 + c*4 + q

typedef unsigned short ushortT;
typedef __attribute__((ext_vector_type(8))) short short8;
typedef __attribute__((ext_vector_type(4))) float floatx4;

__device__ __forceinline__ unsigned short f2bf(float f) {
  union { float f; unsigned u; } v; v.f = f;
  unsigned r = v.u + 0x7FFF + ((v.u >> 16) & 1);
  return (unsigned short)(r >> 16);
}
__device__ __forceinline__ float bf2f(unsigned short h) {
  union { unsigned u; float f; } v; v.u = ((unsigned)h) << 16;
  return v.f;
}

// native exp2: single v_exp_f32, no OCML denormal fixup (inputs here are
// moderate-negative products; flush-to-zero below ~-126 is fine).
__device__ __forceinline__ float ex2(float x) {
#if defined(__has_builtin)
#if __has_builtin(__builtin_amdgcn_exp2f)
  return __builtin_amdgcn_exp2f(x);
#else
  return exp2f(x);
#endif
#else
  return exp2f(x);
#endif
}

// ---------------- fp32 -> bf16 conversion ----------------
__global__ __launch_bounds__(256) void cvt_bf16_kernel(const float* __restrict__ in,
                                                       ushortT* __restrict__ out, int n4) {
  int i = blockIdx.x * 256 + threadIdx.x;
  if (i >= n4) return;
  float4 v = ((const float4*)in)[i];
  ushort4 o;
  o.x = f2bf(v.x); o.y = f2bf(v.y); o.z = f2bf(v.z); o.w = f2bf(v.w);
  ((ushort4*)out)[i] = o;
}

// ---------------- zero fill (float4 granules) ----------------
__global__ __launch_bounds__(256) void zero_kernel(float4* __restrict__ p) {
  p[blockIdx.x * 256 + threadIdx.x] = make_float4(0.f, 0.f, 0.f, 0.f);
}

// ---------------- bf16 NT GEMM: C[m,n] = sum_k A[m,k]*B[n,k] ----------------
__global__ __launch_bounds__(256) void gemm_nt(const ushortT* __restrict__ A,
                                               const ushortT* __restrict__ Bm,
                                               float* __restrict__ Cf, ushortT* __restrict__ Cb,
                                               int M, int N, int K, int out_bf16, int G)
{
  __shared__ ushortT As[128 * 64];
  __shared__ ushortT Bs[128 * 64];
  int tid = threadIdx.x;
  int wave = tid >> 6, lane = tid & 63;
  int gid = blockIdx.y * gridDim.x + blockIdx.x;
  int per_sg = G * gridDim.y;
  int sg = gid / per_sg, r = gid % per_sg;
  int bm = r / G;
  int bn = sg * G + (r % G);
  const ushortT* Abase = A + (size_t)bm * 128 * K;
  const ushortT* Bbase = Bm + (size_t)bn * 128 * K;
  int lm = lane & 15, lq = lane >> 4;
  int wm = (wave >> 1) * 64, wn = (wave & 1) * 64;
  int rloc = lane >> 3;
  int c_st = (lane & 7) * 8;
  floatx4 acc[4][4] = {};

  for (int k0 = 0; k0 < K; k0 += 64) {
    __syncthreads();
    #pragma unroll
    for (int j = 0; j < 4; j++) {
      int t = wave * 4 + j;
      const ushortT* ga = Abase + (size_t)(t * 8 + rloc) * K + k0 + c_st;
      const ushortT* gb = Bbase + (size_t)(t * 8 + rloc) * K + k0 + c_st;
      __builtin_amdgcn_global_load_lds((const __attribute__((address_space(1))) void*)ga,
                                       (__attribute__((address_space(3))) void*)(As + t * 512),
                                       16, 0, 0);
      __builtin_amdgcn_global_load_lds((const __attribute__((address_space(1))) void*)gb,
                                       (__attribute__((address_space(3))) void*)(Bs + t * 512),
                                       16, 0, 0);
    }
    __syncthreads();
    #pragma unroll
    for (int ks = 0; ks < 2; ks++) {
      short8 af[4], bfv[4];
      #pragma unroll
      for (int i = 0; i < 4; i++)
        af[i] = *(const short8*)(As + (wm + i * 16 + lm) * 64 + ks * 32 + lq * 8);
      #pragma unroll
      for (int j2 = 0; j2 < 4; j2++)
        bfv[j2] = *(const short8*)(Bs + (wn + j2 * 16 + lm) * 64 + ks * 32 + lq * 8);
      #pragma unroll
      for (int i = 0; i < 4; i++)
        #pragma unroll
        for (int j2 = 0; j2 < 4; j2++)
          acc[i][j2] = __builtin_amdgcn_mfma_f32_16x16x32_bf16(af[i], bfv[j2], acc[i][j2], 0, 0, 0);
    }
  }
  #pragma unroll
  for (int i = 0; i < 4; i++) {
    #pragma unroll
    for (int j2 = 0; j2 < 4; j2++) {
      int mg = bm * 128 + wm + i * 16 + lq * 4;
      int ng = bn * 128 + wn + j2 * 16 + lm;
      #pragma unroll
      for (int q = 0; q < 4; q++) {
        size_t off = (size_t)(mg + q) * N + ng;
        if (out_bf16) Cb[off] = f2bf(acc[i][j2][q]);
        else          Cf[off] = acc[i][j2][q];
      }
    }
  }
}

// ---------------- causal depthwise conv(k=4) + silu, bf16 in/out ----------------
__global__ __launch_bounds__(256) void conv_silu_kernel(const ushortT* __restrict__ xz,
                                                        const float* __restrict__ w,
                                                        const float* __restrict__ bias,
                                                        ushortT* __restrict__ xc, int reverse)
{
  int idx = blockIdx.x * 256 + threadIdx.x;
  int p4 = idx & 1023;
  int rb = idx >> 10;
  int b = rb & 3, d = rb >> 2;
  int wq = p4 >> 6, c = p4 & 63;
  int l0 = c * 64 + wq * 4;                    // plain (or reversed-seq) position
  const ushortT* xin = xz + (size_t)d * NCOLS + b * L_SZ;
  float w0 = w[d * 4], w1 = w[d * 4 + 1], w2 = w[d * 4 + 2], w3 = w[d * 4 + 3];
  float bv = bias[d];
  float xv[8];
  float r0, r1, r2, r3;
  if (!reverse) {
    if (l0 >= 4) {
      ushort4 a = *(const ushort4*)(xin + l0 - 4);
      ushort4 cc = *(const ushort4*)(xin + l0);
      xv[0]=bf2f(a.x); xv[1]=bf2f(a.y); xv[2]=bf2f(a.z); xv[3]=bf2f(a.w);
      xv[4]=bf2f(cc.x); xv[5]=bf2f(cc.y); xv[6]=bf2f(cc.z); xv[7]=bf2f(cc.w);
    } else {
      #pragma unroll
      for (int i = 0; i < 8; i++) { int p = l0 - 4 + i; xv[i] = (p >= 0) ? bf2f(xin[p]) : 0.f; }
    }
    r0 = bv + w0*xv[1] + w1*xv[2] + w2*xv[3] + w3*xv[4];
    r1 = bv + w0*xv[2] + w1*xv[3] + w2*xv[4] + w3*xv[5];
    r2 = bv + w0*xv[3] + w1*xv[4] + w2*xv[5] + w3*xv[6];
    r3 = bv + w0*xv[4] + w1*xv[5] + w2*xv[6] + w3*xv[7];
  } else {
    int base = 4092 - l0;
    if (l0 >= 4) {
      ushort4 a = *(const ushort4*)(xin + base);
      ushort4 cc = *(const ushort4*)(xin + base + 4);
      xv[0]=bf2f(a.x); xv[1]=bf2f(a.y); xv[2]=bf2f(a.z); xv[3]=bf2f(a.w);
      xv[4]=bf2f(cc.x); xv[5]=bf2f(cc.y); xv[6]=bf2f(cc.z); xv[7]=bf2f(cc.w);
    } else {
      #pragma unroll
      for (int i = 0; i < 8; i++) { int p = base + i; xv[i] = (p <= 4095) ? bf2f(xin[p]) : 0.f; }
    }
    r0 = bv + w0*xv[6] + w1*xv[5] + w2*xv[4] + w3*xv[3];
    r1 = bv + w0*xv[5] + w1*xv[4] + w2*xv[3] + w3*xv[2];
    r2 = bv + w0*xv[4] + w1*xv[3] + w2*xv[2] + w3*xv[1];
    r3 = bv + w0*xv[3] + w1*xv[2] + w2*xv[1] + w3*xv[0];
  }
  ushort4 o;
  o.x = f2bf(r0 / (1.f + __expf(-r0)));
  o.y = f2bf(r1 / (1.f + __expf(-r1)));
  o.z = f2bf(r2 / (1.f + __expf(-r2)));
  o.w = f2bf(r3 / (1.f + __expf(-r3)));
  *(ushort4*)(xc + (size_t)d * NCOLS + b * L_SZ + p4 * 4) = o;
}

// ---------------- x_proj GEMM (fp32 vector), K-split x3 + atomic accumulate ----------------
// grid (NCOLS/64, 3). Outputs must be pre-zeroed.
__global__ __launch_bounds__(256) void xdbl_kernel(const ushortT* __restrict__ xc,
                                                   const float* __restrict__ W, // (80,1536)
                                                   float* __restrict__ dtr,
                                                   float* __restrict__ Bt,
                                                   float* __restrict__ Ct)
{
  __shared__ float xcs[32 * 68];
  __shared__ float Ws[80 * 32];
  int tid = threadIdx.x;
  int n0 = blockIdx.x * 64;
  int kbase = blockIdx.y * 512;
  int tm = tid >> 4, tn = tid & 15;
  float acc[5][4] = {};
  for (int k0 = kbase; k0 < kbase + 512; k0 += 32) {
    __syncthreads();
    {
      int kk = tid >> 3, c8 = (tid & 7) * 8;
      const ushortT* src = xc + (size_t)(k0 + kk) * NCOLS + n0 + c8;
      ushort4 a = *(const ushort4*)src;
      ushort4 b = *(const ushort4*)(src + 4);
      float* dst = xcs + kk * 68 + c8;
      dst[0]=bf2f(a.x); dst[1]=bf2f(a.y); dst[2]=bf2f(a.z); dst[3]=bf2f(a.w);
      dst[4]=bf2f(b.x); dst[5]=bf2f(b.y); dst[6]=bf2f(b.z); dst[7]=bf2f(b.w);
    }
    for (int i = tid; i < 80 * 32; i += 256) {
      int m = i >> 5, kk = i & 31;
      Ws[i] = W[(size_t)m * DINNER + k0 + kk];
    }
    __syncthreads();
    #pragma unroll 8
    for (int kk = 0; kk < 32; kk++) {
      const float* xr = xcs + kk * 68 + tn * 4;
      float x0 = xr[0], x1 = xr[1], x2 = xr[2], x3 = xr[3];
      #pragma unroll
      for (int im = 0; im < 5; im++) {
        float wv = Ws[(tm * 5 + im) * 32 + kk];
        acc[im][0] += wv * x0; acc[im][1] += wv * x1;
        acc[im][2] += wv * x2; acc[im][3] += wv * x3;
      }
    }
  }
  #pragma unroll
  for (int im = 0; im < 5; im++) {
    int m = tm * 5 + im;
    #pragma unroll
    for (int j = 0; j < 4; j++) {
      int n = n0 + tn * 4 + j;
      float v = acc[im][j];
      if (m < 48)      atomicAdd(&dtr[(size_t)m * NCOLS + n], v);
      else if (m < 64) atomicAdd(&Bt[(size_t)n * 16 + (m - 48)], v);
      else             atomicAdd(&Ct[(size_t)n * 16 + (m - 64)], v);
    }
  }
}

// ---------------- dt = softplus(W @ dtr + bias), bf16 out (permuted cols) ----------------
__global__ __launch_bounds__(256) void dt_kernel(const float* __restrict__ dtr,
                                                 const float* __restrict__ W, // (1536,48)
                                                 const float* __restrict__ bias,
                                                 ushortT* __restrict__ dtb)
{
  __shared__ float sD[48 * 68];
  __shared__ float sW[48 * 68];
  int tid = threadIdx.x;
  int n0 = blockIdx.x * 64, d0 = blockIdx.y * 64;
  for (int i = tid; i < 48 * 64; i += 256) {
    int r = i >> 6, c = i & 63;
    sD[r * 68 + c] = dtr[(size_t)r * NCOLS + n0 + c];
  }
  for (int i = tid; i < 64 * 48; i += 256) {
    int dd = i / 48, k = i - dd * 48;
    sW[k * 68 + dd] = W[(size_t)d0 * 48 + i];
  }
  __syncthreads();
  int tn = tid & 15, tm = tid >> 4;
  float acc[4][4];
  #pragma unroll
  for (int i = 0; i < 4; i++) {
    float bv = bias[d0 + tm * 4 + i];
    #pragma unroll
    for (int j = 0; j < 4; j++) acc[i][j] = bv;
  }
  #pragma unroll 6
  for (int k = 0; k < 48; k++) {
    float4 wv = *(const float4*)(sW + k * 68 + tm * 4);
    float4 xv = *(const float4*)(sD + k * 68 + tn * 4);
    float wa[4] = { wv.x, wv.y, wv.z, wv.w };
    float xa[4] = { xv.x, xv.y, xv.z, xv.w };
    #pragma unroll
    for (int i = 0; i < 4; i++)
      #pragma unroll
      for (int j = 0; j < 4; j++)
        acc[i][j] += wa[i] * xa[j];
  }
  #pragma unroll
  for (int i = 0; i < 4; i++) {
    int d = d0 + tm * 4 + i;
    ushort4 o;
    float a0 = acc[i][0], a1 = acc[i][1], a2 = acc[i][2], a3 = acc[i][3];
    o.x = f2bf((a0 > 20.f) ? a0 : log1pf(__expf(a0)));
    o.y = f2bf((a1 > 20.f) ? a1 : log1pf(__expf(a1)));
    o.z = f2bf((a2 > 20.f) ? a2 : log1pf(__expf(a2)));
    o.w = f2bf((a3 > 20.f) ? a3 : log1pf(__expf(a3)));
    *(ushort4*)(dtb + (size_t)d * NCOLS + n0 + tn * 4) = o;
  }
}

// ---------------- chunked selective scan v8: y1 in LDS + u/t prefetch ----------------
// Block 256 = 2 d-rows x 64 chunks x 2 state-halves (8 states/thread).
// y1 kept in LDS between passes (no global round-trip); u/t prefetched one
// w-iteration ahead (wrap-indexed, branchless); pass2 unrolled x2.
// Grid (DINNER/2, B_SZ) = (768,4).
__global__ __launch_bounds__(256) void scan_kernel8(const ushortT* __restrict__ u,  // XC (read-only now)
                                                    const ushortT* __restrict__ dt,
                                                    const float* __restrict__ Bt,
                                                    const float* __restrict__ Ct,
                                                    const float* __restrict__ A_log,
                                                    const float* __restrict__ Dp,
                                                    ushortT* __restrict__ y, int reverse)
{
  __shared__ float Hs[32 * 65];
  __shared__ float Ss[2 * 64];
  __shared__ float Y1s[2 * 4096];    // y1 buffer, per d-row x position (permuted idx)
  int tid = threadIdx.x;
  int hf = tid & 1;                  // state half
  int c  = (tid >> 1) & 63;          // chunk
  int dl = tid >> 7;                 // d-row within block (0,1)
  int b = blockIdx.y;
  int d = blockIdx.x * 2 + dl;
  int ns0 = hf * 8;

  float Av2[8];
  #pragma unroll
  for (int n = 0; n < 8; n++)
    Av2[n] = -__expf(A_log[d * 16 + ns0 + n]) * 1.442695040888963f;  // A*log2(e)
  float Dv = Dp[d];

  const ushortT* ur = u + (size_t)d * NCOLS + b * L_SZ + c * 4;
  const ushortT* tr = dt + (size_t)d * NCOLS + b * L_SZ + c * 4;
  const float*   Bp = Bt + (size_t)b * L_SZ * 16 + ns0;
  const float*   Cp = Ct + (size_t)b * L_SZ * 16 + ns0;

  float h[8];
  float S = 0.f;
  #pragma unroll
  for (int n = 0; n < 8; n++) h[n] = 0.f;

  // ---- pass 1: y1 (to LDS) + chunk summaries; u/t prefetched one w ahead ----
  ushort4 u4 = *(const ushort4*)(ur);
  ushort4 t4 = *(const ushort4*)(tr);
  for (int w = 0; w < 16; w++) {
    int wn1 = (w + 1) & 15;                       // wrap: always in-bounds
    ushort4 u4n = *(const ushort4*)(ur + wn1 * 256);
    ushort4 t4n = *(const ushort4*)(tr + wn1 * 256);
    float uv[4] = { bf2f(u4.x), bf2f(u4.y), bf2f(u4.z), bf2f(u4.w) };
    float tv[4] = { bf2f(t4.x), bf2f(t4.y), bf2f(t4.z), bf2f(t4.w) };
    const float* Bw = Bp + (size_t)(w * 256 + c * 4) * 16;
    const float* Cw = Cp + (size_t)(w * 256 + c * 4) * 16;
    float yo[4];
    #pragma unroll
    for (int q = 0; q < 4; q++) {
      float tq = tv[q];
      float dtu = tq * uv[q];
      float4 b0 = *(const float4*)(Bw + q * 16);
      float4 b1 = *(const float4*)(Bw + q * 16 + 4);
      float4 c0 = *(const float4*)(Cw + q * 16);
      float4 c1 = *(const float4*)(Cw + q * 16 + 4);
      float Bf[8] = { b0.x,b0.y,b0.z,b0.w, b1.x,b1.y,b1.z,b1.w };
      float Cv[8] = { c0.x,c0.y,c0.z,c0.w, c1.x,c1.y,c1.z,c1.w };
      float a0 = 0.f, a1 = 0.f;
      #pragma unroll
      for (int n = 0; n < 4; n++) {
        float e = ex2(tq * Av2[n]);
        h[n] = h[n] * e + Bf[n] * dtu;
        a0 += h[n] * Cv[n];
      }
      #pragma unroll
      for (int n = 4; n < 8; n++) {
        float e = ex2(tq * Av2[n]);
        h[n] = h[n] * e + Bf[n] * dtu;
        a1 += h[n] * Cv[n];
      }
      yo[q] = a0 + a1;
      S += tq;
    }
    // batched cross-lane sum (4 independent shuffles, one wait)
    float os0 = __shfl_xor(yo[0], 1);
    float os1 = __shfl_xor(yo[1], 1);
    float os2 = __shfl_xor(yo[2], 1);
    float os3 = __shfl_xor(yo[3], 1);
    if (hf == 0) {
      float4 yq;
      yq.x = yo[0] + os0 + Dv * uv[0];
      yq.y = yo[1] + os1 + Dv * uv[1];
      yq.z = yo[2] + os2 + Dv * uv[2];
      yq.w = yo[3] + os3 + Dv * uv[3];
      *(float4*)(Y1s + dl * 4096 + w * 256 + c * 4) = yq;
    }
    u4 = u4n; t4 = t4n;
  }
  #pragma unroll
  for (int n = 0; n < 8; n++)
    Hs[(dl * 16 + ns0 + n) * 65 + c] = h[n];
  if (hf == 0) Ss[dl * 64 + c] = S;
  __syncthreads();

  // ---- combine: 32 threads = (d-row, state); serial over 64 chunks ----
  if (tid < 32) {
    int dl2 = tid >> 4, n2 = tid & 15;
    float Ac = -__expf(A_log[(blockIdx.x * 2 + dl2) * 16 + n2]) * 1.442695040888963f;
    float hsv = 0.f;
    int row = tid;
    for (int cc = 0; cc < NCHUNK; cc++) {
      int idx = row * 65 + cc;
      float tmp = Hs[idx];
      Hs[idx] = hsv;                   // h at chunk start
      hsv = ex2(Ac * Ss[dl2 * 64 + cc]) * hsv + tmp;
    }
  }
  __syncthreads();
  float hsr[8];
  #pragma unroll
  for (int n = 0; n < 8; n++) hsr[n] = Hs[(dl * 16 + ns0 + n) * 65 + c];

  // ---- pass 2 (chain-free): y = y1 + C . (exp2(Av2*T) ⊙ h_start) ----
  ushortT* yrow = y + (size_t)d * NCOLS + b * L_SZ;
  float T = 0.f;
  #pragma unroll 2
  for (int w = 0; w < 16; w++) {
    ushort4 t4b = *(const ushort4*)(tr + w * 256);
    float tv[4]  = { bf2f(t4b.x), bf2f(t4b.y), bf2f(t4b.z), bf2f(t4b.w) };
    float4 y1q = *(const float4*)(Y1s + dl * 4096 + w * 256 + c * 4);  // both hf: broadcast
    const float* Cw = Cp + (size_t)(w * 256 + c * 4) * 16;
    float co[4];
    #pragma unroll
    for (int q = 0; q < 4; q++) {
      T += tv[q];
      float4 c0 = *(const float4*)(Cw + q * 16);
      float4 c1 = *(const float4*)(Cw + q * 16 + 4);
      float Cv[8] = { c0.x,c0.y,c0.z,c0.w, c1.x,c1.y,c1.z,c1.w };
      float a0 = 0.f, a1 = 0.f;
      #pragma unroll
      for (int n = 0; n < 4; n++)
        a0 += (ex2(Av2[n] * T) * hsr[n]) * Cv[n];
      #pragma unroll
      for (int n = 4; n < 8; n++)
        a1 += (ex2(Av2[n] * T) * hsr[n]) * Cv[n];
      co[q] = a0 + a1;
    }
    // batched cross-lane sum
    float os0 = __shfl_xor(co[0], 1);
    float os1 = __shfl_xor(co[1], 1);
    float os2 = __shfl_xor(co[2], 1);
    float os3 = __shfl_xor(co[3], 1);
    if (hf == 0) {
      float yq0 = y1q.x + co[0] + os0;
      float yq1 = y1q.y + co[1] + os1;
      float yq2 = y1q.z + co[2] + os2;
      float yq3 = y1q.w + co[3] + os3;
      if (!reverse) {
        ushort4 o;
        o.x = f2bf(yq0); o.y = f2bf(yq1); o.z = f2bf(yq2); o.w = f2bf(yq3);
        *(ushort4*)(yrow + w * 256 + c * 4) = o;
      } else {
        // plain l = 4095 - lrev maps to permuted (15-w)*256 + (63-c)*4 + (3-q)
        ushort4* dst = (ushort4*)(yrow + (15 - w) * 256 + (63 - c) * 4);
        ushort4 old = *dst;
        ushort4 o;
        o.x = f2bf(bf2f(old.x) + yq3);
        o.y = f2bf(bf2f(old.y) + yq2);
        o.z = f2bf(bf2f(old.z) + yq1);
        o.w = f2bf(bf2f(old.w) + yq0);
        *dst = o;
      }
    }
  }
}

// ---------------- inner = bf16( y * silu(z) ), transposed to (n, d) ----------------
__global__ __launch_bounds__(256) void inner_kernel(const ushortT* __restrict__ y,
                                                    const ushortT* __restrict__ xz,
                                                    ushortT* __restrict__ innerb)
{
  __shared__ float tile[64 * 65];
  int n0 = blockIdx.x * 64, d0 = blockIdx.y * 64;
  int tid = threadIdx.x;
  int c = tid & 63, rq = tid >> 6;
  int bseg = n0 & ~4095;                        // b * L_SZ
  int cch = (n0 & 4095) >> 6;                   // chunk (fixed for this tile)
  int poff = bseg + cch * 4 + (c >> 2) * 256 + (c & 3);  // permuted column of plain n0+c
  #pragma unroll
  for (int r = 0; r < 16; r++) {
    int dd = rq + r * 4;
    float yv = bf2f(y[(size_t)(d0 + dd) * NCOLS + poff]);
    float zv = bf2f(xz[(size_t)(DINNER + d0 + dd) * NCOLS + n0 + c]);
    float sv = zv / (1.f + __expf(-zv));
    tile[dd * 65 + c] = yv * sv;
  }
  __syncthreads();
  #pragma unroll
  for (int r = 0; r < 16; r++) {
    int nn = rq + r * 4;
    innerb[(size_t)(n0 + nn) * DINNER + d0 + c] = f2bf(tile[c * 65 + nn]);
  }
}

extern "C" void kernel_launch(void* const* d_in, const int* in_sizes, int n_in,
                              void* d_out, int out_size, void* d_ws, size_t ws_size,
                              hipStream_t stream)
{
  const float* x          = (const float*)d_in[0];
  const float* in_proj_w  = (const float*)d_in[1];
  const float* out_proj_w = (const float*)d_in[2];
  const float* conv_w     = (const float*)d_in[3];
  const float* conv_b     = (const float*)d_in[4];
  const float* xproj_w    = (const float*)d_in[5];
  const float* dt_w       = (const float*)d_in[6];
  const float* dt_b       = (const float*)d_in[7];
  const float* A_log      = (const float*)d_in[8];
  const float* Dp         = (const float*)d_in[9];
  const float* conv_w_b   = (const float*)d_in[10];
  const float* conv_b_b   = (const float*)d_in[11];
  const float* xproj_w_b  = (const float*)d_in[12];
  const float* dt_w_b     = (const float*)d_in[13];
  const float* dt_b_b     = (const float*)d_in[14];
  const float* A_log_b    = (const float*)d_in[15];
  const float* D_b        = (const float*)d_in[16];

  // --- workspace layout (peak 199.25 MiB), DTB in d_out ---
  char* ws = (char*)d_ws;
  ushortT* XZ   = (ushortT*)(ws + 0);
  ushortT* XC   = (ushortT*)(ws + 100663296);
  ushortT* YB   = (ushortT*)(ws + 150994944);
  float*   DTR  = (float*)  (ws + 201326592);
  float*   BT   = (float*)  (ws + 204472320);
  float*   CT   = (float*)  (ws + 205520896);
  ushortT* WOB  = (ushortT*)(ws + 206569472);
  ushortT* XB   = (ushortT*)(ws + 100663296);  // overlay on XC region (P0/P1 only)
  ushortT* WIB  = (ushortT*)(ws + 150994944);  // overlay on YB region (P0/P1 only)
  ushortT* DTB  = (ushortT*)d_out;             // 48 MiB exactly
  ushortT* INNER = XZ;                         // overlay on XZ x-half
  float* OUT = (float*)d_out;

  // bf16 conversions
  cvt_bf16_kernel<<<12288, 256, 0, stream>>>(x, XB, 3145728);
  cvt_bf16_kernel<<<2304, 256, 0, stream>>>(in_proj_w, WIB, 589824);
  cvt_bf16_kernel<<<1152, 256, 0, stream>>>(out_proj_w, WOB, 294912);

  // xz = in_proj_w @ x^T : (3072 x 16384), bf16 out; G=16 swizzle for L2 reuse
  gemm_nt<<<dim3(128, 24), 256, 0, stream>>>(WIB, XB, nullptr, XZ, E2, NCOLS, DIM, 1, 16);

  // forward direction
  conv_silu_kernel<<<24576, 256, 0, stream>>>(XZ, conv_w, conv_b, XC, 0);
  zero_kernel<<<1280, 256, 0, stream>>>((float4*)DTR);   // DTR+BT+CT = 5 MiB
  xdbl_kernel<<<dim3(256, 3), 256, 0, stream>>>(XC, xproj_w, DTR, BT, CT);
  dt_kernel<<<dim3(256, 24), 256, 0, stream>>>(DTR, dt_w, dt_b, DTB);
  scan_kernel8<<<dim3(768, 4), 256, 0, stream>>>(XC, DTB, BT, CT, A_log, Dp, YB, 0);

  // reverse direction (reversed coords; y added at original positions, permuted layout)
  conv_silu_kernel<<<24576, 256, 0, stream>>>(XZ, conv_w_b, conv_b_b, XC, 1);
  zero_kernel<<<1280, 256, 0, stream>>>((float4*)DTR);
  xdbl_kernel<<<dim3(256, 3), 256, 0, stream>>>(XC, xproj_w_b, DTR, BT, CT);
  dt_kernel<<<dim3(256, 24), 256, 0, stream>>>(DTR, dt_w_b, dt_b_b, DTB);
  scan_kernel8<<<dim3(768, 4), 256, 0, stream>>>(XC, DTB, BT, CT, A_log_b, D_b, YB, 1);

  // inner = bf16( y * silu(z) ) transposed to (n, d); un-permutes y
  inner_kernel<<<dim3(256, 24), 256, 0, stream>>>(YB, XZ, INNER);

  // out = inner @ out_proj_w^T : (16384 x 768), fp32 out
  gemm_nt<<<dim3(6, 128), 256, 0, stream>>>(INNER, WOB, OUT, nullptr, NCOLS, DIM, DINNER, 0, 6);
}